// Round 7
// baseline (365.361 us; speedup 1.0000x reference)
//
#include <hip/hip_runtime.h>
#include <hip/hip_bf16.h>
#include <math.h>

#define N_NODES 20000
#define N_EDGES 320000
#define IN_DIM 128
#define HID 256
#define HEADS 8
#define DH 32
#define LAYERS 3
#define NUM_GRAPHS 64
#define OUT_DIM 10
#define SLOPE 0.2f

// src-bucketed CSR: bucket = src >> 12 (4096 nodes = 2 MB of fsb per bucket)
#define NBKT 5
#define N_BINS (N_NODES * NBKT)      // 100000
#define N_BINS4 (N_BINS / 4)         // 25000

// scan chunks aligned to node boundaries: 1020 bins = 204 nodes * 5 buckets.
#define CHUNK_I4 255                 // int4s per chunk (1020 bins)
#define N_CHUNKS 99                  // ceil(100000 / 1020)

#define GEMM_TILES 626               // 313 m-tiles x 2 n-tiles
#define COUNT_BLOCKS 1250            // 320000 / 256

typedef __bf16 bf16x8 __attribute__((ext_vector_type(8)));
typedef float f32x4 __attribute__((ext_vector_type(4)));

static __device__ __forceinline__ unsigned short f2bfbits(float v) {
    __bf16 b = (__bf16)v;
    return __builtin_bit_cast(unsigned short, b);
}
// unpack 8 bf16 (in a uint4) -> 8 fp32, exact
static __device__ __forceinline__ void unpack8(uint4 u, float* f) {
    unsigned p0 = u.x, p1 = u.y, p2 = u.z, p3 = u.w;
    f[0] = __builtin_bit_cast(float, p0 << 16);
    f[1] = __builtin_bit_cast(float, p0 & 0xffff0000u);
    f[2] = __builtin_bit_cast(float, p1 << 16);
    f[3] = __builtin_bit_cast(float, p1 & 0xffff0000u);
    f[4] = __builtin_bit_cast(float, p2 << 16);
    f[5] = __builtin_bit_cast(float, p2 & 0xffff0000u);
    f[6] = __builtin_bit_cast(float, p3 << 16);
    f[7] = __builtin_bit_cast(float, p3 & 0xffff0000u);
}

static __device__ __forceinline__ bf16x8 ldfrag(const unsigned short* p) {
    return __builtin_bit_cast(bf16x8, *(const uint4*)p);
}

// ---------------- prep: feature cast, weight transpose/cast ----------------
#define CAST_N4 (N_NODES * IN_DIM / 4)                 // 640000
#define WTRANS_TOTAL (IN_DIM * HID + 6 * HID * HID)    // 425984
#define PREP_TOTAL (CAST_N4 + WTRANS_TOTAL)            // 1065984 = 4164 * 256
#define PREP_BLOCKS (PREP_TOTAL / 256)                 // 4164 (exact)

static __device__ void prep_item(int idx,
                                 const float* __restrict__ feat,
                                 const float* __restrict__ Win,
                                 const float* __restrict__ Wsrc,
                                 const float* __restrict__ Wdst,
                                 unsigned short* __restrict__ featH,
                                 unsigned short* __restrict__ WinT,
                                 unsigned short* __restrict__ WT) {
    if (idx < CAST_N4) {
        float4 v = ((const float4*)feat)[idx];
        ushort4 o;
        o.x = f2bfbits(v.x); o.y = f2bfbits(v.y);
        o.z = f2bfbits(v.z); o.w = f2bfbits(v.w);
        ((ushort4*)featH)[idx] = o;
    } else {
        int j = idx - CAST_N4;
        if (j < IN_DIM * HID) {
            int n = j / IN_DIM, k = j % IN_DIM;
            WinT[j] = f2bfbits(Win[k * HID + n]);
        } else {
            int r6 = j - IN_DIM * HID;
            int mat = r6 >> 16;
            int r = r6 & 65535;
            int n = r >> 8, k = r & 255;
            const float* base = (mat < 3) ? (Wsrc + (size_t)mat * 65536)
                                          : (Wdst + (size_t)(mat - 3) * 65536);
            WT[r6] = f2bfbits(base[k * 256 + n]);
        }
    }
}

// ---------------- wide scan: block u scans its 1020-bin chunk; base via one atomicAdd ----------------
static __device__ void scans_unit(int u, int t, const int* __restrict__ cnt,
                                  int* __restrict__ cglob, int* __restrict__ offs,
                                  int* __restrict__ cursor, int* si) {
    int idx4 = u * CHUNK_I4 + t;               // t in [0,256); active t < 255
    bool act = (t < CHUNK_I4) && (idx4 < N_BINS4);
    int4 x = make_int4(0, 0, 0, 0);
    if (act) x = ((const int4*)cnt)[idx4];
    int tsum = x.x + x.y + x.z + x.w;
    int v = tsum;
#pragma unroll
    for (int d = 1; d < 64; d <<= 1) {
        int w = __shfl_up(v, d, 64);
        if ((t & 63) >= d) v += w;
    }
    if ((t & 63) == 63) si[4 + (t >> 6)] = v;
    __syncthreads();
    if (t == 0) {
        int S = si[4] + si[5] + si[6] + si[7];
        si[0] = atomicAdd(cglob, S);           // 99 atomics total -- no contention
    }
    __syncthreads();
    int base = si[0];
    int wid = t >> 6;
    int waveoff = 0;
    if (wid > 0) waveoff += si[4];
    if (wid > 1) waveoff += si[5];
    if (wid > 2) waveoff += si[6];
    int ex = base + waveoff + (v - tsum);
    if (act) {
        int4 o;
        o.x = ex; o.y = ex + x.x; o.z = o.y + x.y; o.w = o.z + x.z;
        ((int4*)offs)[idx4] = o;
        ((int4*)cursor)[idx4] = o;
    }
}

// ---------------- MFMA GEMM tile: M64 x N128, BK=32, fully register-direct ----------------
// NO LDS, NO barriers. Lane fragments are plain 16B global loads:
//   A frag  = A[m0+mrow0(+16)+l15][k0 + quad*8 .. +8]
//   B frag  = BT[n0+ncb+t4*16+l15][k0 + quad*8 .. +8]   (weights, L2-resident)
// One-step-ahead register prefetch; the compiler pipelines with per-use vmcnt.
// This removes the per-K-step __syncthreads + vmcnt(0) drain that stalled the
// LDS-staged variant (46us at 3.8% MfmaUtil, R5 counters).
template <int DUAL>
static __device__ void gemm_tile(int mt, int nt, int t,
                                 const unsigned short* __restrict__ Ah,
                                 const unsigned short* __restrict__ BT1,
                                 const float* __restrict__ bias1,
                                 unsigned short* __restrict__ O1,
                                 const unsigned short* __restrict__ BT2,
                                 const float* __restrict__ bias2,
                                 unsigned short* __restrict__ O2,
                                 int M, int K, int N) {
    const int wv = t >> 6, lane = t & 63, quad = lane >> 4, l15 = lane & 15;
    const int m0 = mt * 64, n0 = nt * 128;
    const int mrow0 = (wv >> 1) * 32;
    const int ncb = (wv & 1) * 64;

    int r0 = m0 + mrow0 + l15;      if (r0 >= M) r0 = M - 1;
    int r1 = m0 + mrow0 + 16 + l15; if (r1 >= M) r1 = M - 1;
    const unsigned short* Ap0 = Ah + (size_t)r0 * K + quad * 8;
    const unsigned short* Ap1 = Ah + (size_t)r1 * K + quad * 8;

    const unsigned short* B1p[4];
    const unsigned short* B2p[4];
#pragma unroll
    for (int t4 = 0; t4 < 4; ++t4) {
        int brow = n0 + ncb + t4 * 16 + l15;
        B1p[t4] = BT1 + (size_t)brow * K + quad * 8;
        if (DUAL) B2p[t4] = BT2 + (size_t)brow * K + quad * 8;
    }

    f32x4 zero = {0.f, 0.f, 0.f, 0.f};
    f32x4 acc1[2][4], acc2[2][4];
#pragma unroll
    for (int mi = 0; mi < 2; ++mi)
#pragma unroll
        for (int t4 = 0; t4 < 4; ++t4) { acc1[mi][t4] = zero; acc2[mi][t4] = zero; }

    // prologue: step-0 fragments
    bf16x8 aC0 = ldfrag(Ap0), aC1 = ldfrag(Ap1);
    bf16x8 bC1[4], bC2[4];
#pragma unroll
    for (int t4 = 0; t4 < 4; ++t4) {
        bC1[t4] = ldfrag(B1p[t4]);
        if (DUAL) bC2[t4] = ldfrag(B2p[t4]);
    }

    for (int k0 = 0; k0 < K; k0 += 32) {
        bf16x8 aN0, aN1, bN1[4], bN2[4];
        bool more = (k0 + 32 < K);
        if (more) {   // prefetch next step while current MFMAs run
            aN0 = ldfrag(Ap0 + k0 + 32);
            aN1 = ldfrag(Ap1 + k0 + 32);
#pragma unroll
            for (int t4 = 0; t4 < 4; ++t4) {
                bN1[t4] = ldfrag(B1p[t4] + k0 + 32);
                if (DUAL) bN2[t4] = ldfrag(B2p[t4] + k0 + 32);
            }
        }
#pragma unroll
        for (int t4 = 0; t4 < 4; ++t4) {
            acc1[0][t4] = __builtin_amdgcn_mfma_f32_16x16x32_bf16(aC0, bC1[t4], acc1[0][t4], 0, 0, 0);
            acc1[1][t4] = __builtin_amdgcn_mfma_f32_16x16x32_bf16(aC1, bC1[t4], acc1[1][t4], 0, 0, 0);
            if (DUAL) {
                acc2[0][t4] = __builtin_amdgcn_mfma_f32_16x16x32_bf16(aC0, bC2[t4], acc2[0][t4], 0, 0, 0);
                acc2[1][t4] = __builtin_amdgcn_mfma_f32_16x16x32_bf16(aC1, bC2[t4], acc2[1][t4], 0, 0, 0);
            }
        }
        if (more) {
            aC0 = aN0; aC1 = aN1;
#pragma unroll
            for (int t4 = 0; t4 < 4; ++t4) {
                bC1[t4] = bN1[t4];
                if (DUAL) bC2[t4] = bN2[t4];
            }
        }
    }

    float bia1[4], bia2[4];
#pragma unroll
    for (int t4 = 0; t4 < 4; ++t4) {
        bia1[t4] = bias1[n0 + ncb + t4 * 16 + l15];
        bia2[t4] = DUAL ? bias2[n0 + ncb + t4 * 16 + l15] : 0.f;
    }
#pragma unroll
    for (int mi = 0; mi < 2; ++mi) {
#pragma unroll
        for (int t4 = 0; t4 < 4; ++t4) {
            int gn = n0 + ncb + t4 * 16 + l15;
#pragma unroll
            for (int r = 0; r < 4; ++r) {
                int gm = m0 + mrow0 + mi * 16 + quad * 4 + r;
                if (gm < M) {
                    float v = acc1[mi][t4][r] + bia1[t4];
                    O1[(size_t)gm * N + gn] = f2bfbits(v);
                    if (DUAL) {
                        float v2 = acc2[mi][t4][r] + bia2[t4];
                        O2[(size_t)gm * N + gn] = f2bfbits(v2);
                    }
                }
            }
        }
    }
}

// ---------------- GATv2 aggregation (proven code; end from offs+cnt) ----------------
static __device__ void agg_unit(int u, int t,
                                const unsigned short* __restrict__ fsb,
                                const unsigned short* __restrict__ fdb,
                                unsigned short* __restrict__ hb,
                                const int* __restrict__ offs,
                                const int* __restrict__ cnt,
                                const int* __restrict__ csr_src,
                                const float* __restrict__ attn_l) {
    int node = u * 8 + (t >> 5);
    if (node >= N_NODES) return;
    int l32 = t & 31;
    int dbase = l32 * 8;
    int abase = (l32 >> 2) * DH + (l32 & 3) * 8;

    float a[8];
#pragma unroll
    for (int j = 0; j < 8; ++j) a[j] = attn_l[abase + j];

    float fdv[8];
    unpack8(*(const uint4*)(fdb + (size_t)node * HID + dbase), fdv);

    float ssum0 = 0.f, ssum1 = 0.f;
    float acc0[8], acc1[8];
#pragma unroll
    for (int j = 0; j < 8; ++j) { acc0[j] = 0.f; acc1[j] = 0.f; }

    auto procE = [&](uint4 uu, float* acc, float& ssum) {
        float fsv[8];
        unpack8(uu, fsv);
        float p = 0.f;
#pragma unroll
        for (int j = 0; j < 8; ++j) {
            float e = fsv[j] + fdv[j];
            e = fmaxf(e, SLOPE * e);   // leakyrelu (slope<1)
            p += e * a[j];
        }
        p += __shfl_xor(p, 1, 64);
        p += __shfl_xor(p, 2, 64);
        float w = __expf(p);
        ssum += w;
#pragma unroll
        for (int j = 0; j < 8; ++j) acc[j] += w * fsv[j];
    };

    const unsigned short* fsl = fsb + dbase;
    int b0 = node * NBKT;
    int beg = offs[b0];
    int end = offs[b0 + NBKT - 1] + cnt[b0 + NBKT - 1];  // chunk-local contiguity
    int nfull = (end - beg) >> 2;
    const int limit = beg + nfull * 4;

    uint4 cu0, cu1, cu2, cu3;
    int ci0, ci1, ci2, ci3;
    int base = beg + 8;
    bool have = (nfull >= 1);
    bool haveN = (nfull >= 2);
    if (have) {
        int s0 = csr_src[beg], s1 = csr_src[beg + 1];
        int s2 = csr_src[beg + 2], s3 = csr_src[beg + 3];
        if (haveN) {
            ci0 = csr_src[beg + 4]; ci1 = csr_src[beg + 5];
            ci2 = csr_src[beg + 6]; ci3 = csr_src[beg + 7];
        }
        cu0 = *(const uint4*)(fsl + (size_t)s0 * HID);
        cu1 = *(const uint4*)(fsl + (size_t)s1 * HID);
        cu2 = *(const uint4*)(fsl + (size_t)s2 * HID);
        cu3 = *(const uint4*)(fsl + (size_t)s3 * HID);
    }
    while (have) {
        uint4 nu0, nu1, nu2, nu3;
        int ni0, ni1, ni2, ni3;
        if (haveN) {
            nu0 = *(const uint4*)(fsl + (size_t)ci0 * HID);
            nu1 = *(const uint4*)(fsl + (size_t)ci1 * HID);
            nu2 = *(const uint4*)(fsl + (size_t)ci2 * HID);
            nu3 = *(const uint4*)(fsl + (size_t)ci3 * HID);
        }
        bool haveNN = (base + 4 <= limit);
        if (haveNN) {
            ni0 = csr_src[base]; ni1 = csr_src[base + 1];
            ni2 = csr_src[base + 2]; ni3 = csr_src[base + 3];
        }
        base += 4;
        procE(cu0, acc0, ssum0);
        procE(cu1, acc1, ssum1);
        procE(cu2, acc0, ssum0);
        procE(cu3, acc1, ssum1);
        if (haveN) { cu0 = nu0; cu1 = nu1; cu2 = nu2; cu3 = nu3; }
        if (haveNN) { ci0 = ni0; ci1 = ni1; ci2 = ni2; ci3 = ni3; }
        have = haveN; haveN = haveNN;
    }
    for (int idx = limit; idx < end; ++idx) {
        int sv = csr_src[idx];
        procE(*(const uint4*)(fsl + (size_t)sv * HID), acc0, ssum0);
    }

    float ssum = ssum0 + ssum1;
    float acc[8];
#pragma unroll
    for (int j = 0; j < 8; ++j) acc[j] = acc0[j] + acc1[j];

    float inv = ssum > 0.f ? 1.f / ssum : 0.f;
    float hv[8];
    unpack8(*(const uint4*)(hb + (size_t)node * HID + dbase), hv);
    unsigned short ob[8];
#pragma unroll
    for (int j = 0; j < 8; ++j) {
        float o = fmaxf(acc[j] * inv + hv[j], 0.f);
        ob[j] = f2bfbits(o);
    }
    *(uint4*)(hb + (size_t)node * HID + dbase) = *(uint4*)ob;
}

// ---------------- D1: prep || count ----------------
__global__ void prep_count_kernel(const float* __restrict__ feat,
                                  const float* __restrict__ Win,
                                  const float* __restrict__ Wsrc,
                                  const float* __restrict__ Wdst,
                                  unsigned short* __restrict__ featH,
                                  unsigned short* __restrict__ WinT,
                                  unsigned short* __restrict__ WT,
                                  const int* __restrict__ src,
                                  const int* __restrict__ dst,
                                  int* __restrict__ cnt) {
    int bid = blockIdx.x;
    if (bid < PREP_BLOCKS) {
        prep_item(bid * 256 + threadIdx.x, feat, Win, Wsrc, Wdst, featH, WinT, WT);
    } else {
        int e = (bid - PREP_BLOCKS) * 256 + threadIdx.x;
        if (e < N_EDGES) atomicAdd(&cnt[dst[e] * NBKT + (src[e] >> 12)], 1);
    }
}

// ---------------- D2: input-projection GEMM || wide chunk scan ----------------
__global__ __launch_bounds__(256, 2) void gemm0_scan_kernel(
    const unsigned short* __restrict__ featH, const unsigned short* __restrict__ WinT,
    const float* __restrict__ b_in, unsigned short* __restrict__ hb,
    const int* __restrict__ cnt, int* __restrict__ cglob,
    int* __restrict__ offs, int* __restrict__ cursor) {
    __shared__ int si[8];
    int bid = blockIdx.x;
    if (bid < GEMM_TILES) {
        gemm_tile<0>(bid >> 1, bid & 1, threadIdx.x, featH, WinT, b_in, hb,
                     (const unsigned short*)nullptr, (const float*)nullptr,
                     (unsigned short*)nullptr, N_NODES, IN_DIM, HID);
    } else {
        scans_unit(bid - GEMM_TILES, threadIdx.x, cnt, cglob, offs, cursor, si);
    }
}

// ---------------- D3: layer-0 dual GEMM || CSR fill ----------------
__global__ __launch_bounds__(256, 2) void gemm1_fill_kernel(
    const unsigned short* __restrict__ hb,
    const unsigned short* __restrict__ WTs, const float* __restrict__ bs,
    unsigned short* __restrict__ fsb,
    const unsigned short* __restrict__ WTd, const float* __restrict__ bd,
    unsigned short* __restrict__ fdb,
    const int* __restrict__ src, const int* __restrict__ dst,
    int* __restrict__ cursor, int* __restrict__ csr_src) {
    int bid = blockIdx.x;
    if (bid < GEMM_TILES) {
        gemm_tile<1>(bid >> 1, bid & 1, threadIdx.x, hb, WTs, bs, fsb, WTd, bd, fdb,
                     N_NODES, HID, HID);
    } else {
        int e = (bid - GEMM_TILES) * 256 + threadIdx.x;
        if (e < N_EDGES) {
            int sv = src[e];
            int p = atomicAdd(&cursor[dst[e] * NBKT + (sv >> 12)], 1);
            csr_src[p] = sv;
        }
    }
}

// ---------------- standalone dual GEMM (layers 1,2) ----------------
__global__ __launch_bounds__(256, 2) void gemm_kernel(
    const unsigned short* __restrict__ Ah,
    const unsigned short* __restrict__ BT1, const float* __restrict__ bias1,
    unsigned short* __restrict__ O1,
    const unsigned short* __restrict__ BT2, const float* __restrict__ bias2,
    unsigned short* __restrict__ O2) {
    gemm_tile<1>(blockIdx.x, blockIdx.y, threadIdx.x, Ah, BT1, bias1, O1,
                 BT2, bias2, O2, N_NODES, HID, HID);
}

// ---------------- aggregation dispatch (XCD-aware bijective block swizzle, T1/m204) ----------------
__global__ __launch_bounds__(256) void agg_kernel(const unsigned short* __restrict__ fsb,
                                                  const unsigned short* __restrict__ fdb,
                                                  unsigned short* __restrict__ hb,
                                                  const int* __restrict__ offs,
                                                  const int* __restrict__ cnt,
                                                  const int* __restrict__ csr_src,
                                                  const float* __restrict__ attn_l) {
    int nwg = gridDim.x;                 // 2500 (not %8) -> bijective variant
    int q = nwg >> 3, r = nwg & 7;
    int xcd = blockIdx.x & 7, idx = blockIdx.x >> 3;
    int u = (xcd < r) ? xcd * (q + 1) + idx
                      : r * (q + 1) + (xcd - r) * q + idx;
    agg_unit(u, threadIdx.x, fsb, fdb, hb, offs, cnt, csr_src, attn_l);
}

// ---------------- D9: fused pool + classifier (one block per graph) ----------------
__global__ __launch_bounds__(256) void poolcls_kernel(
    const unsigned short* __restrict__ hb, const int* __restrict__ gid,
    const float* __restrict__ Wc1, const float* __restrict__ bc1,
    const float* __restrict__ Wc2, const float* __restrict__ bc2,
    const float* __restrict__ Wc3, const float* __restrict__ bc3,
    float* __restrict__ out) {
    __shared__ float part[8 * HID];
    __shared__ float xin[HID];
    __shared__ float x1[HID];
    __shared__ float x2[HID / 2];
    int g = blockIdx.x, t = threadIdx.x;

    int lo = 0, hi = N_NODES;
    while (lo < hi) { int mid = (lo + hi) >> 1; if (gid[mid] < g) lo = mid + 1; else hi = mid; }
    int s0 = lo;
    hi = N_NODES;
    while (lo < hi) { int mid = (lo + hi) >> 1; if (gid[mid] < g + 1) lo = mid + 1; else hi = mid; }
    int e0 = lo;

    int r = t >> 5;
    int fb = (t & 31) * 8;
    float a0[8], a1[8];
#pragma unroll
    for (int j = 0; j < 8; ++j) { a0[j] = 0.f; a1[j] = 0.f; }
    int n = s0 + r;
    for (; n + 8 < e0; n += 16) {
        uint4 u0 = *(const uint4*)(hb + (size_t)n * HID + fb);
        uint4 u1 = *(const uint4*)(hb + (size_t)(n + 8) * HID + fb);
        float f0[8], f1[8];
        unpack8(u0, f0); unpack8(u1, f1);
#pragma unroll
        for (int j = 0; j < 8; ++j) { a0[j] += f0[j]; a1[j] += f1[j]; }
    }
    if (n < e0) {
        uint4 u0 = *(const uint4*)(hb + (size_t)n * HID + fb);
        float f0[8];
        unpack8(u0, f0);
#pragma unroll
        for (int j = 0; j < 8; ++j) a0[j] += f0[j];
    }
#pragma unroll
    for (int j = 0; j < 8; ++j) part[r * HID + fb + j] = a0[j] + a1[j];
    __syncthreads();
    {
        float s = 0.f;
#pragma unroll
        for (int r2 = 0; r2 < 8; ++r2) s += part[r2 * HID + t];
        xin[t] = s;
    }
    __syncthreads();

    {
        float acc = bc1[t];
        for (int k = 0; k < HID; ++k) acc += xin[k] * Wc1[k * HID + t];
        x1[t] = fmaxf(acc, 0.f);
    }
    __syncthreads();
    if (t < HID / 2) {
        float acc = bc2[t];
        for (int k = 0; k < HID; ++k) acc += x1[k] * Wc2[k * (HID / 2) + t];
        x2[t] = fmaxf(acc, 0.f);
    }
    __syncthreads();
    if (t < OUT_DIM) {
        float acc = bc3[t];
        for (int k = 0; k < HID / 2; ++k) acc += x2[k] * Wc3[k * OUT_DIM + t];
        out[g * OUT_DIM + t] = acc;
    }
}

// ---------------- launch: 10 dispatches (memset + 9 kernels) ----------------
extern "C" void kernel_launch(void* const* d_in, const int* in_sizes, int n_in,
                              void* d_out, int out_size, void* d_ws, size_t ws_size,
                              hipStream_t stream) {
    const float* feature = (const float*)d_in[0];
    const float* W_in   = (const float*)d_in[1];
    const float* b_in   = (const float*)d_in[2];
    const float* W_src  = (const float*)d_in[3];
    const float* b_src  = (const float*)d_in[4];
    const float* W_dst  = (const float*)d_in[5];
    const float* b_dst  = (const float*)d_in[6];
    const float* attn   = (const float*)d_in[7];
    const float* Wc1    = (const float*)d_in[8];
    const float* bc1    = (const float*)d_in[9];
    const float* Wc2    = (const float*)d_in[10];
    const float* bc2    = (const float*)d_in[11];
    const float* Wc3    = (const float*)d_in[12];
    const float* bc3    = (const float*)d_in[13];
    const int* src     = (const int*)d_in[14];
    const int* dst     = (const int*)d_in[15];
    const int* gid     = (const int*)d_in[16];
    float* out = (float*)d_out;

    char* w = (char*)d_ws;
    auto alloc = [&](size_t bytes) -> void* {
        void* p = (void*)w;
        w += (bytes + 255) & ~(size_t)255;
        return p;
    };
    unsigned short* hb  = (unsigned short*)alloc((size_t)N_NODES * HID * 2);  // unified bf16 h
    unsigned short* fsb = (unsigned short*)alloc((size_t)N_NODES * HID * 2);
    unsigned short* fdb = (unsigned short*)alloc((size_t)N_NODES * HID * 2);
    int* cnt     = (int*)alloc((size_t)N_BINS * 4);   // cnt + cglob zeroed by one memset
    int* cglob   = (int*)alloc(4);
    int* offs    = (int*)alloc((size_t)(N_BINS + 4) * 4);
    int* cursor  = (int*)alloc((size_t)N_BINS * 4);
    int* csr_src = (int*)alloc((size_t)N_EDGES * 4);
    unsigned short* WinT = (unsigned short*)alloc((size_t)IN_DIM * HID * 2);
    unsigned short* WT   = (unsigned short*)alloc((size_t)6 * HID * HID * 2);
    unsigned short* featH = (unsigned short*)alloc((size_t)N_NODES * IN_DIM * 2);
    (void)alloc(4096);  // slack for clamped staging overreach

    // D0: zero cnt + cglob (contiguous region, one memset)
    size_t zlen = (size_t)((char*)offs - (char*)cnt);
    hipMemsetAsync(cnt, 0, zlen, stream);

    // D1: prep (feature cast + weight transposes) || edge-bin count
    hipLaunchKernelGGL(prep_count_kernel, dim3(PREP_BLOCKS + COUNT_BLOCKS), dim3(256), 0, stream,
                       feature, W_in, W_src, W_dst, featH, WinT, WT, src, dst, cnt);

    // D2: input-projection GEMM || wide chunk scan (99 blocks, 1 atomic each)
    hipLaunchKernelGGL(gemm0_scan_kernel, dim3(GEMM_TILES + N_CHUNKS), dim3(256), 0, stream,
                       featH, WinT, b_in, hb, cnt, cglob, offs, cursor);

    // D3: layer-0 dual GEMM || CSR fill
    hipLaunchKernelGGL(gemm1_fill_kernel, dim3(GEMM_TILES + COUNT_BLOCKS), dim3(256), 0, stream,
                       hb, WT, b_src, fsb, WT + 3 * 65536, b_dst, fdb,
                       src, dst, cursor, csr_src);

    // D4..D8: agg0, gemm_l1, agg1, gemm_l2, agg2
    for (int l = 0; l < LAYERS; ++l) {
        hipLaunchKernelGGL(agg_kernel, dim3(N_NODES / 8), dim3(256), 0, stream,
                           fsb, fdb, hb, offs, cnt, csr_src, attn + (size_t)l * HEADS * DH);
        if (l + 1 < LAYERS) {
            hipLaunchKernelGGL(gemm_kernel, dim3(313, 2), dim3(256), 0, stream,
                               hb, WT + (size_t)(l + 1) * 65536, b_src + (size_t)(l + 1) * HID, fsb,
                               WT + (size_t)(4 + l) * 65536, b_dst + (size_t)(l + 1) * HID, fdb);
        }
    }

    // D9: fused graph-sum-pool + classifier
    hipLaunchKernelGGL(poolcls_kernel, dim3(NUM_GRAPHS), dim3(256), 0, stream,
                       hb, gid, Wc1, bc1, Wc2, bc2, Wc3, bc3, out);
}

// Round 8
// 312.313 us; speedup vs baseline: 1.1699x; 1.1699x over previous
//
#include <hip/hip_runtime.h>
#include <hip/hip_bf16.h>
#include <math.h>

#define N_NODES 20000
#define N_EDGES 320000
#define IN_DIM 128
#define HID 256
#define HEADS 8
#define DH 32
#define LAYERS 3
#define NUM_GRAPHS 64
#define OUT_DIM 10
#define SLOPE 0.2f

// src-bucketed CSR: bucket = src >> 12 (4096 nodes = 2 MB of fsb per bucket)
#define NBKT 5
#define N_BINS (N_NODES * NBKT)      // 100000
#define N_BINS4 (N_BINS / 4)         // 25000

// scan chunks aligned to node boundaries: 1020 bins = 204 nodes * 5 buckets.
#define CHUNK_I4 255                 // int4s per chunk (1020 bins)
#define N_CHUNKS 99                  // ceil(100000 / 1020)

#define GEMM_TILES 626               // 313 m-tiles x 2 n-tiles
#define COUNT_BLOCKS 1250            // 320000 / 256

typedef __bf16 bf16x8 __attribute__((ext_vector_type(8)));
typedef float f32x4 __attribute__((ext_vector_type(4)));

static __device__ __forceinline__ unsigned short f2bfbits(float v) {
    __bf16 b = (__bf16)v;
    return __builtin_bit_cast(unsigned short, b);
}
// unpack 8 bf16 (in a uint4) -> 8 fp32, exact
static __device__ __forceinline__ void unpack8(uint4 u, float* f) {
    unsigned p0 = u.x, p1 = u.y, p2 = u.z, p3 = u.w;
    f[0] = __builtin_bit_cast(float, p0 << 16);
    f[1] = __builtin_bit_cast(float, p0 & 0xffff0000u);
    f[2] = __builtin_bit_cast(float, p1 << 16);
    f[3] = __builtin_bit_cast(float, p1 & 0xffff0000u);
    f[4] = __builtin_bit_cast(float, p2 << 16);
    f[5] = __builtin_bit_cast(float, p2 & 0xffff0000u);
    f[6] = __builtin_bit_cast(float, p3 << 16);
    f[7] = __builtin_bit_cast(float, p3 & 0xffff0000u);
}

// async 16B global->LDS (DMA, wave-uniform LDS base + lane*16)
typedef const __attribute__((address_space(1))) unsigned int* as1_u32p;
typedef __attribute__((address_space(3))) unsigned int* as3_u32p;
static __device__ __forceinline__ void async_cp16(const unsigned short* g, unsigned short* l) {
    __builtin_amdgcn_global_load_lds((as1_u32p)g, (as3_u32p)l, 16, 0, 0);
}

// ---------------- prep: feature cast, weight transpose/cast ----------------
#define CAST_N4 (N_NODES * IN_DIM / 4)                 // 640000
#define WTRANS_TOTAL (IN_DIM * HID + 6 * HID * HID)    // 425984
#define PREP_TOTAL (CAST_N4 + WTRANS_TOTAL)            // 1065984 = 4164 * 256
#define PREP_BLOCKS (PREP_TOTAL / 256)                 // 4164 (exact)

static __device__ void prep_item(int idx,
                                 const float* __restrict__ feat,
                                 const float* __restrict__ Win,
                                 const float* __restrict__ Wsrc,
                                 const float* __restrict__ Wdst,
                                 unsigned short* __restrict__ featH,
                                 unsigned short* __restrict__ WinT,
                                 unsigned short* __restrict__ WT) {
    if (idx < CAST_N4) {
        float4 v = ((const float4*)feat)[idx];
        ushort4 o;
        o.x = f2bfbits(v.x); o.y = f2bfbits(v.y);
        o.z = f2bfbits(v.z); o.w = f2bfbits(v.w);
        ((ushort4*)featH)[idx] = o;
    } else {
        int j = idx - CAST_N4;
        if (j < IN_DIM * HID) {
            int n = j / IN_DIM, k = j % IN_DIM;
            WinT[j] = f2bfbits(Win[k * HID + n]);
        } else {
            int r6 = j - IN_DIM * HID;
            int mat = r6 >> 16;
            int r = r6 & 65535;
            int n = r >> 8, k = r & 255;
            const float* base = (mat < 3) ? (Wsrc + (size_t)mat * 65536)
                                          : (Wdst + (size_t)(mat - 3) * 65536);
            WT[r6] = f2bfbits(base[k * 256 + n]);
        }
    }
}

// ---------------- wide scan: block u scans its 1020-bin chunk; base via one atomicAdd ----------------
static __device__ void scans_unit(int u, int t, const int* __restrict__ cnt,
                                  int* __restrict__ cglob, int* __restrict__ offs,
                                  int* si) {
    int idx4 = u * CHUNK_I4 + t;               // t in [0,256); active t < 255
    bool act = (t < CHUNK_I4) && (idx4 < N_BINS4);
    int4 x = make_int4(0, 0, 0, 0);
    if (act) x = ((const int4*)cnt)[idx4];
    int tsum = x.x + x.y + x.z + x.w;
    int v = tsum;
#pragma unroll
    for (int d = 1; d < 64; d <<= 1) {
        int w = __shfl_up(v, d, 64);
        if ((t & 63) >= d) v += w;
    }
    if ((t & 63) == 63) si[4 + (t >> 6)] = v;
    __syncthreads();
    if (t == 0) {
        int S = si[4] + si[5] + si[6] + si[7];
        si[0] = atomicAdd(cglob, S);           // 99 atomics total -- no contention
    }
    __syncthreads();
    int base = si[0];
    int wid = t >> 6;
    int waveoff = 0;
    if (wid > 0) waveoff += si[4];
    if (wid > 1) waveoff += si[5];
    if (wid > 2) waveoff += si[6];
    int ex = base + waveoff + (v - tsum);
    if (act) {
        int4 o;
        o.x = ex; o.y = ex + x.x; o.z = o.y + x.y; o.w = o.z + x.z;
        ((int4*)offs)[idx4] = o;
    }
}

// ---------------- MFMA GEMM tile: M64 x N128, BK=32, regA + LDS-dbuf B (R6 best) ----------------
template <int DUAL>
static __device__ void gemm_tile(int mt, int nt, int t,
                                 const unsigned short* __restrict__ Ah,
                                 const unsigned short* __restrict__ BT1,
                                 const float* __restrict__ bias1,
                                 unsigned short* __restrict__ O1,
                                 const unsigned short* __restrict__ BT2,
                                 const float* __restrict__ bias2,
                                 unsigned short* __restrict__ O2,
                                 int M, int K, int N,
                                 unsigned short* Bs1P, unsigned short* Bs2P) {
    const int wv = t >> 6, lane = t & 63, quad = lane >> 4, l15 = lane & 15;
    const int m0 = mt * 64, n0 = nt * 128;

    // B staging (byte-identical to proven path)
    const int sB0 = wv * 64 + lane, sB1v = sB0 + 256;
    const int rB0 = sB0 >> 2, cB0 = (sB0 & 3) ^ ((rB0 >> 1) & 3);
    const int rB1 = sB1v >> 2, cB1 = (sB1v & 3) ^ ((rB1 >> 1) & 3);
    const size_t offB0 = (size_t)(n0 + rB0) * K + cB0 * 8;
    const size_t offB1 = (size_t)(n0 + rB1) * K + cB1 * 8;

    auto issueB = [&](int buf, int k0) {
        async_cp16(BT1 + offB0 + k0, Bs1P + buf * 4096 + wv * 512);
        async_cp16(BT1 + offB1 + k0, Bs1P + buf * 4096 + 2048 + wv * 512);
        if (DUAL) {
            async_cp16(BT2 + offB0 + k0, Bs2P + buf * 4096 + wv * 512);
            async_cp16(BT2 + offB1 + k0, Bs2P + buf * 4096 + 2048 + wv * 512);
        }
    };

    const int mrow0 = (wv >> 1) * 32;
    const int ncb = (wv & 1) * 64;

    // A direct-load row pointers (clamped; clamped rows' results are discarded)
    int r0 = m0 + mrow0 + l15;      if (r0 >= M) r0 = M - 1;
    int r1 = m0 + mrow0 + 16 + l15; if (r1 >= M) r1 = M - 1;
    const unsigned short* Ap0 = Ah + (size_t)r0 * K + quad * 8;
    const unsigned short* Ap1 = Ah + (size_t)r1 * K + quad * 8;

    f32x4 zero = {0.f, 0.f, 0.f, 0.f};
    f32x4 acc1[2][4], acc2[2][4];
#pragma unroll
    for (int mi = 0; mi < 2; ++mi)
#pragma unroll
        for (int t4 = 0; t4 < 4; ++t4) { acc1[mi][t4] = zero; acc2[mi][t4] = zero; }

    issueB(0, 0);
    bf16x8 aC0 = __builtin_bit_cast(bf16x8, *(const uint4*)(Ap0));
    bf16x8 aC1 = __builtin_bit_cast(bf16x8, *(const uint4*)(Ap1));

    int buf = 0;
    for (int k0 = 0; k0 < K; k0 += 32, buf ^= 1) {
        __syncthreads();
        bf16x8 aN0 = aC0, aN1 = aC1;
        if (k0 + 32 < K) {
            issueB(buf ^ 1, k0 + 32);
            aN0 = __builtin_bit_cast(bf16x8, *(const uint4*)(Ap0 + k0 + 32));
            aN1 = __builtin_bit_cast(bf16x8, *(const uint4*)(Ap1 + k0 + 32));
        }
#pragma unroll
        for (int t4 = 0; t4 < 4; ++t4) {
            int brow = ncb + t4 * 16 + l15;
            int boff = brow * 32 + ((quad ^ ((brow >> 1) & 3)) << 3);
            bf16x8 b1 = __builtin_bit_cast(bf16x8, *(const uint4*)(Bs1P + buf * 4096 + boff));
            acc1[0][t4] = __builtin_amdgcn_mfma_f32_16x16x32_bf16(aC0, b1, acc1[0][t4], 0, 0, 0);
            acc1[1][t4] = __builtin_amdgcn_mfma_f32_16x16x32_bf16(aC1, b1, acc1[1][t4], 0, 0, 0);
            if (DUAL) {
                bf16x8 b2 = __builtin_bit_cast(bf16x8, *(const uint4*)(Bs2P + buf * 4096 + boff));
                acc2[0][t4] = __builtin_amdgcn_mfma_f32_16x16x32_bf16(aC0, b2, acc2[0][t4], 0, 0, 0);
                acc2[1][t4] = __builtin_amdgcn_mfma_f32_16x16x32_bf16(aC1, b2, acc2[1][t4], 0, 0, 0);
            }
        }
        aC0 = aN0; aC1 = aN1;
    }

    float bia1[4], bia2[4];
#pragma unroll
    for (int t4 = 0; t4 < 4; ++t4) {
        bia1[t4] = bias1[n0 + ncb + t4 * 16 + l15];
        bia2[t4] = DUAL ? bias2[n0 + ncb + t4 * 16 + l15] : 0.f;
    }
#pragma unroll
    for (int mi = 0; mi < 2; ++mi) {
#pragma unroll
        for (int t4 = 0; t4 < 4; ++t4) {
            int gn = n0 + ncb + t4 * 16 + l15;
#pragma unroll
            for (int r = 0; r < 4; ++r) {
                int gm = m0 + mrow0 + mi * 16 + quad * 4 + r;
                if (gm < M) {
                    float v = acc1[mi][t4][r] + bia1[t4];
                    O1[(size_t)gm * N + gn] = f2bfbits(v);
                    if (DUAL) {
                        float v2 = acc2[mi][t4][r] + bia2[t4];
                        O2[(size_t)gm * N + gn] = f2bfbits(v2);
                    }
                }
            }
        }
    }
}

// ---------------- GATv2 aggregation (proven code; end from offs+cnt) ----------------
static __device__ void agg_unit(int u, int t,
                                const unsigned short* __restrict__ fsb,
                                const unsigned short* __restrict__ fdb,
                                unsigned short* __restrict__ hb,
                                const int* __restrict__ offs,
                                const int* __restrict__ cnt,
                                const int* __restrict__ csr_src,
                                const float* __restrict__ attn_l) {
    int node = u * 8 + (t >> 5);
    if (node >= N_NODES) return;
    int l32 = t & 31;
    int dbase = l32 * 8;
    int abase = (l32 >> 2) * DH + (l32 & 3) * 8;

    float a[8];
#pragma unroll
    for (int j = 0; j < 8; ++j) a[j] = attn_l[abase + j];

    float fdv[8];
    unpack8(*(const uint4*)(fdb + (size_t)node * HID + dbase), fdv);

    float ssum0 = 0.f, ssum1 = 0.f;
    float acc0[8], acc1[8];
#pragma unroll
    for (int j = 0; j < 8; ++j) { acc0[j] = 0.f; acc1[j] = 0.f; }

    auto procE = [&](uint4 uu, float* acc, float& ssum) {
        float fsv[8];
        unpack8(uu, fsv);
        float p = 0.f;
#pragma unroll
        for (int j = 0; j < 8; ++j) {
            float e = fsv[j] + fdv[j];
            e = fmaxf(e, SLOPE * e);   // leakyrelu (slope<1)
            p += e * a[j];
        }
        p += __shfl_xor(p, 1, 64);
        p += __shfl_xor(p, 2, 64);
        float w = __expf(p);
        ssum += w;
#pragma unroll
        for (int j = 0; j < 8; ++j) acc[j] += w * fsv[j];
    };

    const unsigned short* fsl = fsb + dbase;
    int b0 = node * NBKT;
    int beg = offs[b0];
    int end = offs[b0 + NBKT - 1] + cnt[b0 + NBKT - 1];  // chunk-local contiguity
    int nfull = (end - beg) >> 2;
    const int limit = beg + nfull * 4;

    uint4 cu0, cu1, cu2, cu3;
    int ci0, ci1, ci2, ci3;
    int base = beg + 8;
    bool have = (nfull >= 1);
    bool haveN = (nfull >= 2);
    if (have) {
        int s0 = csr_src[beg], s1 = csr_src[beg + 1];
        int s2 = csr_src[beg + 2], s3 = csr_src[beg + 3];
        if (haveN) {
            ci0 = csr_src[beg + 4]; ci1 = csr_src[beg + 5];
            ci2 = csr_src[beg + 6]; ci3 = csr_src[beg + 7];
        }
        cu0 = *(const uint4*)(fsl + (size_t)s0 * HID);
        cu1 = *(const uint4*)(fsl + (size_t)s1 * HID);
        cu2 = *(const uint4*)(fsl + (size_t)s2 * HID);
        cu3 = *(const uint4*)(fsl + (size_t)s3 * HID);
    }
    while (have) {
        uint4 nu0, nu1, nu2, nu3;
        int ni0, ni1, ni2, ni3;
        if (haveN) {
            nu0 = *(const uint4*)(fsl + (size_t)ci0 * HID);
            nu1 = *(const uint4*)(fsl + (size_t)ci1 * HID);
            nu2 = *(const uint4*)(fsl + (size_t)ci2 * HID);
            nu3 = *(const uint4*)(fsl + (size_t)ci3 * HID);
        }
        bool haveNN = (base + 4 <= limit);
        if (haveNN) {
            ni0 = csr_src[base]; ni1 = csr_src[base + 1];
            ni2 = csr_src[base + 2]; ni3 = csr_src[base + 3];
        }
        base += 4;
        procE(cu0, acc0, ssum0);
        procE(cu1, acc1, ssum1);
        procE(cu2, acc0, ssum0);
        procE(cu3, acc1, ssum1);
        if (haveN) { cu0 = nu0; cu1 = nu1; cu2 = nu2; cu3 = nu3; }
        if (haveNN) { ci0 = ni0; ci1 = ni1; ci2 = ni2; ci3 = ni3; }
        have = haveN; haveN = haveNN;
    }
    for (int idx = limit; idx < end; ++idx) {
        int sv = csr_src[idx];
        procE(*(const uint4*)(fsl + (size_t)sv * HID), acc0, ssum0);
    }

    float ssum = ssum0 + ssum1;
    float acc[8];
#pragma unroll
    for (int j = 0; j < 8; ++j) acc[j] = acc0[j] + acc1[j];

    float inv = ssum > 0.f ? 1.f / ssum : 0.f;
    float hv[8];
    unpack8(*(const uint4*)(hb + (size_t)node * HID + dbase), hv);
    unsigned short ob[8];
#pragma unroll
    for (int j = 0; j < 8; ++j) {
        float o = fmaxf(acc[j] * inv + hv[j], 0.f);
        ob[j] = f2bfbits(o);
    }
    *(uint4*)(hb + (size_t)node * HID + dbase) = *(uint4*)ob;
}

// ---------------- D1: prep || count (count now RETURNS slot -> coalesced slot store) ----------------
__global__ void prep_count_kernel(const float* __restrict__ feat,
                                  const float* __restrict__ Win,
                                  const float* __restrict__ Wsrc,
                                  const float* __restrict__ Wdst,
                                  unsigned short* __restrict__ featH,
                                  unsigned short* __restrict__ WinT,
                                  unsigned short* __restrict__ WT,
                                  const int* __restrict__ src,
                                  const int* __restrict__ dst,
                                  int* __restrict__ cnt,
                                  int* __restrict__ slot) {
    int bid = blockIdx.x;
    if (bid < PREP_BLOCKS) {
        prep_item(bid * 256 + threadIdx.x, feat, Win, Wsrc, Wdst, featH, WinT, WT);
    } else {
        int e = (bid - PREP_BLOCKS) * 256 + threadIdx.x;
        if (e < N_EDGES) {
            int bin = dst[e] * NBKT + (src[e] >> 12);
            slot[e] = atomicAdd(&cnt[bin], 1);   // slot within bin, fixed at count time
        }
    }
}

// ---------------- D2: input-projection GEMM || wide chunk scan ----------------
__global__ __launch_bounds__(256, 4) void gemm0_scan_kernel(
    const unsigned short* __restrict__ featH, const unsigned short* __restrict__ WinT,
    const float* __restrict__ b_in, unsigned short* __restrict__ hb,
    const int* __restrict__ cnt, int* __restrict__ cglob,
    int* __restrict__ offs) {
    __shared__ __align__(16) unsigned short smem[8192];
    int bid = blockIdx.x;
    if (bid < GEMM_TILES) {
        gemm_tile<0>(bid >> 1, bid & 1, threadIdx.x, featH, WinT, b_in, hb,
                     (const unsigned short*)nullptr, (const float*)nullptr,
                     (unsigned short*)nullptr, N_NODES, IN_DIM, HID,
                     smem, smem);
    } else {
        scans_unit(bid - GEMM_TILES, threadIdx.x, cnt, cglob, offs,
                   (int*)(void*)smem);
    }
}

// ---------------- D3: layer-0 dual GEMM || atomic-free CSR fill ----------------
__global__ __launch_bounds__(256, 4) void gemm1_fill_kernel(
    const unsigned short* __restrict__ hb,
    const unsigned short* __restrict__ WTs, const float* __restrict__ bs,
    unsigned short* __restrict__ fsb,
    const unsigned short* __restrict__ WTd, const float* __restrict__ bd,
    unsigned short* __restrict__ fdb,
    const int* __restrict__ src, const int* __restrict__ dst,
    const int* __restrict__ offs, const int* __restrict__ slot,
    int* __restrict__ csr_src) {
    __shared__ __align__(16) unsigned short smem[16384];
    int bid = blockIdx.x;
    if (bid < GEMM_TILES) {
        gemm_tile<1>(bid >> 1, bid & 1, threadIdx.x, hb, WTs, bs, fsb, WTd, bd, fdb,
                     N_NODES, HID, HID, smem, smem + 8192);
    } else {
        int e = (bid - GEMM_TILES) * 256 + threadIdx.x;
        if (e < N_EDGES) {
            int sv = src[e];
            int bin = dst[e] * NBKT + (sv >> 12);
            csr_src[offs[bin] + slot[e]] = sv;   // no atomic: slot fixed in D1
        }
    }
}

// ---------------- standalone dual GEMM (layers 1,2) ----------------
__global__ __launch_bounds__(256, 4) void gemm_kernel(
    const unsigned short* __restrict__ Ah,
    const unsigned short* __restrict__ BT1, const float* __restrict__ bias1,
    unsigned short* __restrict__ O1,
    const unsigned short* __restrict__ BT2, const float* __restrict__ bias2,
    unsigned short* __restrict__ O2) {
    __shared__ __align__(16) unsigned short smem[16384];
    gemm_tile<1>(blockIdx.x, blockIdx.y, threadIdx.x, Ah, BT1, bias1, O1,
                 BT2, bias2, O2, N_NODES, HID, HID, smem, smem + 8192);
}

// ---------------- aggregation dispatch (XCD-aware bijective block swizzle, T1/m204) ----------------
__global__ __launch_bounds__(256) void agg_kernel(const unsigned short* __restrict__ fsb,
                                                  const unsigned short* __restrict__ fdb,
                                                  unsigned short* __restrict__ hb,
                                                  const int* __restrict__ offs,
                                                  const int* __restrict__ cnt,
                                                  const int* __restrict__ csr_src,
                                                  const float* __restrict__ attn_l) {
    int nwg = gridDim.x;                 // 2500 (not %8) -> bijective variant
    int q = nwg >> 3, r = nwg & 7;
    int xcd = blockIdx.x & 7, idx = blockIdx.x >> 3;
    int u = (xcd < r) ? xcd * (q + 1) + idx
                      : r * (q + 1) + (xcd - r) * q + idx;
    agg_unit(u, threadIdx.x, fsb, fdb, hb, offs, cnt, csr_src, attn_l);
}

// ---------------- D9: fused pool + classifier (one block per graph) ----------------
__global__ __launch_bounds__(256) void poolcls_kernel(
    const unsigned short* __restrict__ hb, const int* __restrict__ gid,
    const float* __restrict__ Wc1, const float* __restrict__ bc1,
    const float* __restrict__ Wc2, const float* __restrict__ bc2,
    const float* __restrict__ Wc3, const float* __restrict__ bc3,
    float* __restrict__ out) {
    __shared__ float part[8 * HID];
    __shared__ float xin[HID];
    __shared__ float x1[HID];
    __shared__ float x2[HID / 2];
    int g = blockIdx.x, t = threadIdx.x;

    int lo = 0, hi = N_NODES;
    while (lo < hi) { int mid = (lo + hi) >> 1; if (gid[mid] < g) lo = mid + 1; else hi = mid; }
    int s0 = lo;
    hi = N_NODES;
    while (lo < hi) { int mid = (lo + hi) >> 1; if (gid[mid] < g + 1) lo = mid + 1; else hi = mid; }
    int e0 = lo;

    int r = t >> 5;
    int fb = (t & 31) * 8;
    float a0[8], a1[8];
#pragma unroll
    for (int j = 0; j < 8; ++j) { a0[j] = 0.f; a1[j] = 0.f; }
    int n = s0 + r;
    for (; n + 8 < e0; n += 16) {
        uint4 u0 = *(const uint4*)(hb + (size_t)n * HID + fb);
        uint4 u1 = *(const uint4*)(hb + (size_t)(n + 8) * HID + fb);
        float f0[8], f1[8];
        unpack8(u0, f0); unpack8(u1, f1);
#pragma unroll
        for (int j = 0; j < 8; ++j) { a0[j] += f0[j]; a1[j] += f1[j]; }
    }
    if (n < e0) {
        uint4 u0 = *(const uint4*)(hb + (size_t)n * HID + fb);
        float f0[8];
        unpack8(u0, f0);
#pragma unroll
        for (int j = 0; j < 8; ++j) a0[j] += f0[j];
    }
#pragma unroll
    for (int j = 0; j < 8; ++j) part[r * HID + fb + j] = a0[j] + a1[j];
    __syncthreads();
    {
        float s = 0.f;
#pragma unroll
        for (int r2 = 0; r2 < 8; ++r2) s += part[r2 * HID + t];
        xin[t] = s;
    }
    __syncthreads();

    {
        float acc = bc1[t];
        for (int k = 0; k < HID; ++k) acc += xin[k] * Wc1[k * HID + t];
        x1[t] = fmaxf(acc, 0.f);
    }
    __syncthreads();
    if (t < HID / 2) {
        float acc = bc2[t];
        for (int k = 0; k < HID; ++k) acc += x1[k] * Wc2[k * (HID / 2) + t];
        x2[t] = fmaxf(acc, 0.f);
    }
    __syncthreads();
    if (t < OUT_DIM) {
        float acc = bc3[t];
        for (int k = 0; k < HID / 2; ++k) acc += x2[k] * Wc3[k * OUT_DIM + t];
        out[g * OUT_DIM + t] = acc;
    }
}

// ---------------- launch: 10 dispatches (memset + 9 kernels) ----------------
extern "C" void kernel_launch(void* const* d_in, const int* in_sizes, int n_in,
                              void* d_out, int out_size, void* d_ws, size_t ws_size,
                              hipStream_t stream) {
    const float* feature = (const float*)d_in[0];
    const float* W_in   = (const float*)d_in[1];
    const float* b_in   = (const float*)d_in[2];
    const float* W_src  = (const float*)d_in[3];
    const float* b_src  = (const float*)d_in[4];
    const float* W_dst  = (const float*)d_in[5];
    const float* b_dst  = (const float*)d_in[6];
    const float* attn   = (const float*)d_in[7];
    const float* Wc1    = (const float*)d_in[8];
    const float* bc1    = (const float*)d_in[9];
    const float* Wc2    = (const float*)d_in[10];
    const float* bc2    = (const float*)d_in[11];
    const float* Wc3    = (const float*)d_in[12];
    const float* bc3    = (const float*)d_in[13];
    const int* src     = (const int*)d_in[14];
    const int* dst     = (const int*)d_in[15];
    const int* gid     = (const int*)d_in[16];
    float* out = (float*)d_out;

    char* w = (char*)d_ws;
    auto alloc = [&](size_t bytes) -> void* {
        void* p = (void*)w;
        w += (bytes + 255) & ~(size_t)255;
        return p;
    };
    unsigned short* hb  = (unsigned short*)alloc((size_t)N_NODES * HID * 2);  // unified bf16 h
    unsigned short* fsb = (unsigned short*)alloc((size_t)N_NODES * HID * 2);
    unsigned short* fdb = (unsigned short*)alloc((size_t)N_NODES * HID * 2);
    int* cnt     = (int*)alloc((size_t)N_BINS * 4);   // cnt + cglob zeroed by one memset
    int* cglob   = (int*)alloc(4);
    int* offs    = (int*)alloc((size_t)(N_BINS + 4) * 4);
    int* slot    = (int*)alloc((size_t)N_EDGES * 4);
    int* csr_src = (int*)alloc((size_t)N_EDGES * 4);
    unsigned short* WinT = (unsigned short*)alloc((size_t)IN_DIM * HID * 2);
    unsigned short* WT   = (unsigned short*)alloc((size_t)6 * HID * HID * 2);
    unsigned short* featH = (unsigned short*)alloc((size_t)N_NODES * IN_DIM * 2);
    (void)alloc(4096);  // slack for clamped staging overreach

    // D0: zero cnt + cglob (contiguous region, one memset)
    size_t zlen = (size_t)((char*)offs - (char*)cnt);
    hipMemsetAsync(cnt, 0, zlen, stream);

    // D1: prep (feature cast + weight transposes) || edge-bin count (+slot assignment)
    hipLaunchKernelGGL(prep_count_kernel, dim3(PREP_BLOCKS + COUNT_BLOCKS), dim3(256), 0, stream,
                       feature, W_in, W_src, W_dst, featH, WinT, WT, src, dst, cnt, slot);

    // D2: input-projection GEMM || wide chunk scan (99 blocks, 1 atomic each)
    hipLaunchKernelGGL(gemm0_scan_kernel, dim3(GEMM_TILES + N_CHUNKS), dim3(256), 0, stream,
                       featH, WinT, b_in, hb, cnt, cglob, offs);

    // D3: layer-0 dual GEMM || atomic-free CSR fill
    hipLaunchKernelGGL(gemm1_fill_kernel, dim3(GEMM_TILES + COUNT_BLOCKS), dim3(256), 0, stream,
                       hb, WT, b_src, fsb, WT + 3 * 65536, b_dst, fdb,
                       src, dst, offs, slot, csr_src);

    // D4..D8: agg0, gemm_l1, agg1, gemm_l2, agg2
    for (int l = 0; l < LAYERS; ++l) {
        hipLaunchKernelGGL(agg_kernel, dim3(N_NODES / 8), dim3(256), 0, stream,
                           fsb, fdb, hb, offs, cnt, csr_src, attn + (size_t)l * HEADS * DH);
        if (l + 1 < LAYERS) {
            hipLaunchKernelGGL(gemm_kernel, dim3(313, 2), dim3(256), 0, stream,
                               hb, WT + (size_t)(l + 1) * 65536, b_src + (size_t)(l + 1) * HID, fsb,
                               WT + (size_t)(4 + l) * 65536, b_dst + (size_t)(l + 1) * HID, fdb);
        }
    }

    // D9: fused graph-sum-pool + classifier
    hipLaunchKernelGGL(poolcls_kernel, dim3(NUM_GRAPHS), dim3(256), 0, stream,
                       hb, gid, Wc1, bc1, Wc2, bc2, Wc3, bc3, out);
}

// Round 9
// 304.119 us; speedup vs baseline: 1.2014x; 1.0269x over previous
//
#include <hip/hip_runtime.h>
#include <hip/hip_bf16.h>
#include <math.h>

#define N_NODES 20000
#define N_EDGES 320000
#define IN_DIM 128
#define HID 256
#define HEADS 8
#define DH 32
#define LAYERS 3
#define NUM_GRAPHS 64
#define OUT_DIM 10
#define SLOPE 0.2f

// src-bucketed CSR: bucket = src >> 12 (4096 nodes = 2 MB of fsb per bucket)
#define NBKT 5
#define N_BINS (N_NODES * NBKT)      // 100000
#define N_BINS4 (N_BINS / 4)         // 25000

// scan chunks aligned to node boundaries: 1020 bins = 204 nodes * 5 buckets.
#define CHUNK_I4 255                 // int4s per chunk (1020 bins)
#define N_CHUNKS 99                  // ceil(100000 / 1020)

#define GEMM_TILES 626               // 313 m-tiles x 2 n-tiles
#define COUNT_BLOCKS 1250            // 320000 / 256

// prep roles: feature cast blocks, LDS-tiled weight-transpose blocks, count blocks
#define CAST_BLOCKS 2500             // 640000 float4s / 256
#define WT_TILES (16 + 192)          // Win: 2x8 tiles; 6 W mats: 4x8 each
#define PREP_BLOCKS (CAST_BLOCKS + WT_TILES)

typedef __bf16 bf16x8 __attribute__((ext_vector_type(8)));
typedef float f32x4 __attribute__((ext_vector_type(4)));

static __device__ __forceinline__ unsigned short f2bfbits(float v) {
    __bf16 b = (__bf16)v;
    return __builtin_bit_cast(unsigned short, b);
}
// unpack 8 bf16 (in a uint4) -> 8 fp32, exact
static __device__ __forceinline__ void unpack8(uint4 u, float* f) {
    unsigned p0 = u.x, p1 = u.y, p2 = u.z, p3 = u.w;
    f[0] = __builtin_bit_cast(float, p0 << 16);
    f[1] = __builtin_bit_cast(float, p0 & 0xffff0000u);
    f[2] = __builtin_bit_cast(float, p1 << 16);
    f[3] = __builtin_bit_cast(float, p1 & 0xffff0000u);
    f[4] = __builtin_bit_cast(float, p2 << 16);
    f[5] = __builtin_bit_cast(float, p2 & 0xffff0000u);
    f[6] = __builtin_bit_cast(float, p3 << 16);
    f[7] = __builtin_bit_cast(float, p3 & 0xffff0000u);
}

// async 16B global->LDS (DMA, wave-uniform LDS base + lane*16)
typedef const __attribute__((address_space(1))) unsigned int* as1_u32p;
typedef __attribute__((address_space(3))) unsigned int* as3_u32p;
static __device__ __forceinline__ void async_cp16(const unsigned short* g, unsigned short* l) {
    __builtin_amdgcn_global_load_lds((as1_u32p)g, (as3_u32p)l, 16, 0, 0);
}

// ---------------- wide scan: block u scans its 1020-bin chunk; base via one atomicAdd ----------------
static __device__ void scans_unit(int u, int t, const int* __restrict__ cnt,
                                  int* __restrict__ cglob, int* __restrict__ offs,
                                  int* si) {
    int idx4 = u * CHUNK_I4 + t;               // t in [0,256); active t < 255
    bool act = (t < CHUNK_I4) && (idx4 < N_BINS4);
    int4 x = make_int4(0, 0, 0, 0);
    if (act) x = ((const int4*)cnt)[idx4];
    int tsum = x.x + x.y + x.z + x.w;
    int v = tsum;
#pragma unroll
    for (int d = 1; d < 64; d <<= 1) {
        int w = __shfl_up(v, d, 64);
        if ((t & 63) >= d) v += w;
    }
    if ((t & 63) == 63) si[4 + (t >> 6)] = v;
    __syncthreads();
    if (t == 0) {
        int S = si[4] + si[5] + si[6] + si[7];
        si[0] = atomicAdd(cglob, S);           // 99 atomics total -- no contention
    }
    __syncthreads();
    int base = si[0];
    int wid = t >> 6;
    int waveoff = 0;
    if (wid > 0) waveoff += si[4];
    if (wid > 1) waveoff += si[5];
    if (wid > 2) waveoff += si[6];
    int ex = base + waveoff + (v - tsum);
    if (act) {
        int4 o;
        o.x = ex; o.y = ex + x.x; o.z = o.y + x.y; o.w = o.z + x.z;
        ((int4*)offs)[idx4] = o;
    }
}

// ---------------- MFMA GEMM tile: M64 x N128, BK=32, regA + LDS-dbuf B (R6/R8 best) ----------------
template <int DUAL>
static __device__ void gemm_tile(int mt, int nt, int t,
                                 const unsigned short* __restrict__ Ah,
                                 const unsigned short* __restrict__ BT1,
                                 const float* __restrict__ bias1,
                                 unsigned short* __restrict__ O1,
                                 const unsigned short* __restrict__ BT2,
                                 const float* __restrict__ bias2,
                                 unsigned short* __restrict__ O2,
                                 int M, int K, int N,
                                 unsigned short* Bs1P, unsigned short* Bs2P) {
    const int wv = t >> 6, lane = t & 63, quad = lane >> 4, l15 = lane & 15;
    const int m0 = mt * 64, n0 = nt * 128;

    // B staging (byte-identical to proven path)
    const int sB0 = wv * 64 + lane, sB1v = sB0 + 256;
    const int rB0 = sB0 >> 2, cB0 = (sB0 & 3) ^ ((rB0 >> 1) & 3);
    const int rB1 = sB1v >> 2, cB1 = (sB1v & 3) ^ ((rB1 >> 1) & 3);
    const size_t offB0 = (size_t)(n0 + rB0) * K + cB0 * 8;
    const size_t offB1 = (size_t)(n0 + rB1) * K + cB1 * 8;

    auto issueB = [&](int buf, int k0) {
        async_cp16(BT1 + offB0 + k0, Bs1P + buf * 4096 + wv * 512);
        async_cp16(BT1 + offB1 + k0, Bs1P + buf * 4096 + 2048 + wv * 512);
        if (DUAL) {
            async_cp16(BT2 + offB0 + k0, Bs2P + buf * 4096 + wv * 512);
            async_cp16(BT2 + offB1 + k0, Bs2P + buf * 4096 + 2048 + wv * 512);
        }
    };

    const int mrow0 = (wv >> 1) * 32;
    const int ncb = (wv & 1) * 64;

    // A direct-load row pointers (clamped; clamped rows' results are discarded)
    int r0 = m0 + mrow0 + l15;      if (r0 >= M) r0 = M - 1;
    int r1 = m0 + mrow0 + 16 + l15; if (r1 >= M) r1 = M - 1;
    const unsigned short* Ap0 = Ah + (size_t)r0 * K + quad * 8;
    const unsigned short* Ap1 = Ah + (size_t)r1 * K + quad * 8;

    f32x4 zero = {0.f, 0.f, 0.f, 0.f};
    f32x4 acc1[2][4], acc2[2][4];
#pragma unroll
    for (int mi = 0; mi < 2; ++mi)
#pragma unroll
        for (int t4 = 0; t4 < 4; ++t4) { acc1[mi][t4] = zero; acc2[mi][t4] = zero; }

    issueB(0, 0);
    bf16x8 aC0 = __builtin_bit_cast(bf16x8, *(const uint4*)(Ap0));
    bf16x8 aC1 = __builtin_bit_cast(bf16x8, *(const uint4*)(Ap1));

    int buf = 0;
    for (int k0 = 0; k0 < K; k0 += 32, buf ^= 1) {
        __syncthreads();
        bf16x8 aN0 = aC0, aN1 = aC1;
        if (k0 + 32 < K) {
            issueB(buf ^ 1, k0 + 32);
            aN0 = __builtin_bit_cast(bf16x8, *(const uint4*)(Ap0 + k0 + 32));
            aN1 = __builtin_bit_cast(bf16x8, *(const uint4*)(Ap1 + k0 + 32));
        }
#pragma unroll
        for (int t4 = 0; t4 < 4; ++t4) {
            int brow = ncb + t4 * 16 + l15;
            int boff = brow * 32 + ((quad ^ ((brow >> 1) & 3)) << 3);
            bf16x8 b1 = __builtin_bit_cast(bf16x8, *(const uint4*)(Bs1P + buf * 4096 + boff));
            acc1[0][t4] = __builtin_amdgcn_mfma_f32_16x16x32_bf16(aC0, b1, acc1[0][t4], 0, 0, 0);
            acc1[1][t4] = __builtin_amdgcn_mfma_f32_16x16x32_bf16(aC1, b1, acc1[1][t4], 0, 0, 0);
            if (DUAL) {
                bf16x8 b2 = __builtin_bit_cast(bf16x8, *(const uint4*)(Bs2P + buf * 4096 + boff));
                acc2[0][t4] = __builtin_amdgcn_mfma_f32_16x16x32_bf16(aC0, b2, acc2[0][t4], 0, 0, 0);
                acc2[1][t4] = __builtin_amdgcn_mfma_f32_16x16x32_bf16(aC1, b2, acc2[1][t4], 0, 0, 0);
            }
        }
        aC0 = aN0; aC1 = aN1;
    }

    float bia1[4], bia2[4];
#pragma unroll
    for (int t4 = 0; t4 < 4; ++t4) {
        bia1[t4] = bias1[n0 + ncb + t4 * 16 + l15];
        bia2[t4] = DUAL ? bias2[n0 + ncb + t4 * 16 + l15] : 0.f;
    }
#pragma unroll
    for (int mi = 0; mi < 2; ++mi) {
#pragma unroll
        for (int t4 = 0; t4 < 4; ++t4) {
            int gn = n0 + ncb + t4 * 16 + l15;
#pragma unroll
            for (int r = 0; r < 4; ++r) {
                int gm = m0 + mrow0 + mi * 16 + quad * 4 + r;
                if (gm < M) {
                    float v = acc1[mi][t4][r] + bia1[t4];
                    O1[(size_t)gm * N + gn] = f2bfbits(v);
                    if (DUAL) {
                        float v2 = acc2[mi][t4][r] + bia2[t4];
                        O2[(size_t)gm * N + gn] = f2bfbits(v2);
                    }
                }
            }
        }
    }
}

// ---------------- GATv2 aggregation ----------------
// WRITEH=1: write relu(agg+h) back to hb (layers 0,1).
// WRITEH=0: final layer -- skip hb write; block-reduce 8 nodes in LDS and
//           atomicAdd per (graph-run, feature) into hg (gid sorted -> <=8 runs).
template <int WRITEH>
static __device__ void agg_unit(int u, int t,
                                const unsigned short* __restrict__ fsb,
                                const unsigned short* __restrict__ fdb,
                                unsigned short* __restrict__ hb,
                                const int* __restrict__ offs,
                                const int* __restrict__ cnt,
                                const int* __restrict__ csr_src,
                                const float* __restrict__ attn_l,
                                const int* __restrict__ gid,
                                float* __restrict__ hg,
                                float* part, int* gids) {
    int node = u * 8 + (t >> 5);     // grid is exactly 2500*8 = 20000 nodes
    int l32 = t & 31;
    int dbase = l32 * 8;
    int abase = (l32 >> 2) * DH + (l32 & 3) * 8;

    float a[8];
#pragma unroll
    for (int j = 0; j < 8; ++j) a[j] = attn_l[abase + j];

    float fdv[8];
    unpack8(*(const uint4*)(fdb + (size_t)node * HID + dbase), fdv);

    float ssum0 = 0.f, ssum1 = 0.f;
    float acc0[8], acc1[8];
#pragma unroll
    for (int j = 0; j < 8; ++j) { acc0[j] = 0.f; acc1[j] = 0.f; }

    auto procE = [&](uint4 uu, float* acc, float& ssum) {
        float fsv[8];
        unpack8(uu, fsv);
        float p = 0.f;
#pragma unroll
        for (int j = 0; j < 8; ++j) {
            float e = fsv[j] + fdv[j];
            e = fmaxf(e, SLOPE * e);   // leakyrelu (slope<1)
            p += e * a[j];
        }
        p += __shfl_xor(p, 1, 64);
        p += __shfl_xor(p, 2, 64);
        float w = __expf(p);
        ssum += w;
#pragma unroll
        for (int j = 0; j < 8; ++j) acc[j] += w * fsv[j];
    };

    const unsigned short* fsl = fsb + dbase;
    int b0 = node * NBKT;
    int beg = offs[b0];
    int end = offs[b0 + NBKT - 1] + cnt[b0 + NBKT - 1];  // chunk-local contiguity
    int nfull = (end - beg) >> 2;
    const int limit = beg + nfull * 4;

    uint4 cu0, cu1, cu2, cu3;
    int ci0, ci1, ci2, ci3;
    int base = beg + 8;
    bool have = (nfull >= 1);
    bool haveN = (nfull >= 2);
    if (have) {
        int s0 = csr_src[beg], s1 = csr_src[beg + 1];
        int s2 = csr_src[beg + 2], s3 = csr_src[beg + 3];
        if (haveN) {
            ci0 = csr_src[beg + 4]; ci1 = csr_src[beg + 5];
            ci2 = csr_src[beg + 6]; ci3 = csr_src[beg + 7];
        }
        cu0 = *(const uint4*)(fsl + (size_t)s0 * HID);
        cu1 = *(const uint4*)(fsl + (size_t)s1 * HID);
        cu2 = *(const uint4*)(fsl + (size_t)s2 * HID);
        cu3 = *(const uint4*)(fsl + (size_t)s3 * HID);
    }
    while (have) {
        uint4 nu0, nu1, nu2, nu3;
        int ni0, ni1, ni2, ni3;
        if (haveN) {
            nu0 = *(const uint4*)(fsl + (size_t)ci0 * HID);
            nu1 = *(const uint4*)(fsl + (size_t)ci1 * HID);
            nu2 = *(const uint4*)(fsl + (size_t)ci2 * HID);
            nu3 = *(const uint4*)(fsl + (size_t)ci3 * HID);
        }
        bool haveNN = (base + 4 <= limit);
        if (haveNN) {
            ni0 = csr_src[base]; ni1 = csr_src[base + 1];
            ni2 = csr_src[base + 2]; ni3 = csr_src[base + 3];
        }
        base += 4;
        procE(cu0, acc0, ssum0);
        procE(cu1, acc1, ssum1);
        procE(cu2, acc0, ssum0);
        procE(cu3, acc1, ssum1);
        if (haveN) { cu0 = nu0; cu1 = nu1; cu2 = nu2; cu3 = nu3; }
        if (haveNN) { ci0 = ni0; ci1 = ni1; ci2 = ni2; ci3 = ni3; }
        have = haveN; haveN = haveNN;
    }
    for (int idx = limit; idx < end; ++idx) {
        int sv = csr_src[idx];
        procE(*(const uint4*)(fsl + (size_t)sv * HID), acc0, ssum0);
    }

    float ssum = ssum0 + ssum1;
    float acc[8];
#pragma unroll
    for (int j = 0; j < 8; ++j) acc[j] = acc0[j] + acc1[j];

    float inv = ssum > 0.f ? 1.f / ssum : 0.f;
    float hv[8];
    unpack8(*(const uint4*)(hb + (size_t)node * HID + dbase), hv);

    if (WRITEH) {
        unsigned short ob[8];
#pragma unroll
        for (int j = 0; j < 8; ++j) {
            float o = fmaxf(acc[j] * inv + hv[j], 0.f);
            ob[j] = f2bfbits(o);
        }
        *(uint4*)(hb + (size_t)node * HID + dbase) = *(uint4*)ob;
    } else {
        int w = t >> 5;
#pragma unroll
        for (int j = 0; j < 8; ++j)
            part[w * HID + dbase + j] = fmaxf(acc[j] * inv + hv[j], 0.f);
        if (l32 == 0) gids[w] = gid[node];
        __syncthreads();
        // thread t owns feature t; walk the 8 node-rows, flushing on graph change
        float run = 0.f;
        int cur = gids[0];
#pragma unroll
        for (int w2 = 0; w2 < 8; ++w2) {
            int g2 = gids[w2];
            if (g2 != cur) {
                atomicAdd(&hg[(size_t)cur * HID + t], run);
                run = 0.f; cur = g2;
            }
            run += part[w2 * HID + t];
        }
        atomicAdd(&hg[(size_t)cur * HID + t], run);
    }
}

// ---------------- D1: featH cast || LDS-tiled weight transpose || count(+slot) ----------------
__global__ __launch_bounds__(256) void prep_count_kernel(
    const float* __restrict__ feat,
    const float* __restrict__ Win,
    const float* __restrict__ Wsrc,
    const float* __restrict__ Wdst,
    unsigned short* __restrict__ featH,
    unsigned short* __restrict__ WinT,
    unsigned short* __restrict__ WT,
    const int* __restrict__ src,
    const int* __restrict__ dst,
    int* __restrict__ cnt,
    int* __restrict__ slot) {
    __shared__ float Lf[64 * 33];   // 64x32 tile + pad
    int bid = blockIdx.x;
    int t = threadIdx.x;
    if (bid < CAST_BLOCKS) {
        int idx = bid * 256 + t;   // < CAST_N4 by construction (2500*256 = 640000)
        float4 v = ((const float4*)feat)[idx];
        ushort4 o;
        o.x = f2bfbits(v.x); o.y = f2bfbits(v.y);
        o.z = f2bfbits(v.z); o.w = f2bfbits(v.w);
        ((ushort4*)featH)[idx] = o;
    } else if (bid < PREP_BLOCKS) {
        // one 64(k) x 32(n) tile: coalesced f32 row reads -> LDS -> coalesced bf16 col writes
        int b2 = bid - CAST_BLOCKS;
        const float* S;
        unsigned short* D;
        int k0, n0, Kd;
        if (b2 < 16) {                       // W_in: 128(k) x 256(n) -> WinT [256][128]
            S = Win; D = WinT; Kd = IN_DIM;
            k0 = (b2 >> 3) * 64; n0 = (b2 & 7) * 32;
        } else {                             // 6 mats 256x256 -> WT [mat][256][256]
            b2 -= 16;
            int mat = b2 >> 5, tt = b2 & 31;
            S = (mat < 3) ? (Wsrc + (size_t)mat * 65536) : (Wdst + (size_t)(mat - 3) * 65536);
            D = WT + (size_t)mat * 65536; Kd = HID;
            k0 = (tt >> 3) * 64; n0 = (tt & 7) * 32;
        }
        {
            int r = t >> 2, c = (t & 3) * 8;             // read W[k0+r][n0+c .. +8]
            const float* sp = S + (size_t)(k0 + r) * HID + n0 + c;
            float4 v0 = *(const float4*)(sp);
            float4 v1 = *(const float4*)(sp + 4);
            float* lp = Lf + r * 33 + c;
            lp[0] = v0.x; lp[1] = v0.y; lp[2] = v0.z; lp[3] = v0.w;
            lp[4] = v1.x; lp[5] = v1.y; lp[6] = v1.z; lp[7] = v1.w;
        }
        __syncthreads();
        {
            int nn = t >> 3, kk = (t & 7) * 8;           // write D[n0+nn][k0+kk .. +8]
            unsigned short ob[8];
#pragma unroll
            for (int j = 0; j < 8; ++j) ob[j] = f2bfbits(Lf[(kk + j) * 33 + nn]);
            *(uint4*)(D + (size_t)(n0 + nn) * Kd + k0 + kk) = *(uint4*)ob;
        }
    } else {
        int e = (bid - PREP_BLOCKS) * 256 + t;
        if (e < N_EDGES) {
            int bin = dst[e] * NBKT + (src[e] >> 12);
            slot[e] = atomicAdd(&cnt[bin], 1);   // slot within bin, fixed at count time
        }
    }
}

// ---------------- D2: input-projection GEMM || wide chunk scan ----------------
__global__ __launch_bounds__(256, 4) void gemm0_scan_kernel(
    const unsigned short* __restrict__ featH, const unsigned short* __restrict__ WinT,
    const float* __restrict__ b_in, unsigned short* __restrict__ hb,
    const int* __restrict__ cnt, int* __restrict__ cglob,
    int* __restrict__ offs) {
    __shared__ __align__(16) unsigned short smem[8192];
    int bid = blockIdx.x;
    if (bid < GEMM_TILES) {
        gemm_tile<0>(bid >> 1, bid & 1, threadIdx.x, featH, WinT, b_in, hb,
                     (const unsigned short*)nullptr, (const float*)nullptr,
                     (unsigned short*)nullptr, N_NODES, IN_DIM, HID,
                     smem, smem);
    } else {
        scans_unit(bid - GEMM_TILES, threadIdx.x, cnt, cglob, offs,
                   (int*)(void*)smem);
    }
}

// ---------------- D3: layer-0 dual GEMM || atomic-free CSR fill ----------------
__global__ __launch_bounds__(256, 4) void gemm1_fill_kernel(
    const unsigned short* __restrict__ hb,
    const unsigned short* __restrict__ WTs, const float* __restrict__ bs,
    unsigned short* __restrict__ fsb,
    const unsigned short* __restrict__ WTd, const float* __restrict__ bd,
    unsigned short* __restrict__ fdb,
    const int* __restrict__ src, const int* __restrict__ dst,
    const int* __restrict__ offs, const int* __restrict__ slot,
    int* __restrict__ csr_src) {
    __shared__ __align__(16) unsigned short smem[16384];
    int bid = blockIdx.x;
    if (bid < GEMM_TILES) {
        gemm_tile<1>(bid >> 1, bid & 1, threadIdx.x, hb, WTs, bs, fsb, WTd, bd, fdb,
                     N_NODES, HID, HID, smem, smem + 8192);
    } else {
        int e = (bid - GEMM_TILES) * 256 + threadIdx.x;
        if (e < N_EDGES) {
            int sv = src[e];
            int bin = dst[e] * NBKT + (sv >> 12);
            csr_src[offs[bin] + slot[e]] = sv;   // no atomic: slot fixed in D1
        }
    }
}

// ---------------- standalone dual GEMM (layers 1,2) ----------------
__global__ __launch_bounds__(256, 4) void gemm_kernel(
    const unsigned short* __restrict__ Ah,
    const unsigned short* __restrict__ BT1, const float* __restrict__ bias1,
    unsigned short* __restrict__ O1,
    const unsigned short* __restrict__ BT2, const float* __restrict__ bias2,
    unsigned short* __restrict__ O2) {
    __shared__ __align__(16) unsigned short smem[16384];
    gemm_tile<1>(blockIdx.x, blockIdx.y, threadIdx.x, Ah, BT1, bias1, O1,
                 BT2, bias2, O2, N_NODES, HID, HID, smem, smem + 8192);
}

// ---------------- aggregation dispatches (XCD-aware bijective block swizzle, T1/m204) ----------------
static __device__ __forceinline__ int xcd_swz(int b, int nwg) {
    int q = nwg >> 3, r = nwg & 7;
    int xcd = b & 7, idx = b >> 3;
    return (xcd < r) ? xcd * (q + 1) + idx
                     : r * (q + 1) + (xcd - r) * q + idx;
}

__global__ __launch_bounds__(256) void agg_kernel(const unsigned short* __restrict__ fsb,
                                                  const unsigned short* __restrict__ fdb,
                                                  unsigned short* __restrict__ hb,
                                                  const int* __restrict__ offs,
                                                  const int* __restrict__ cnt,
                                                  const int* __restrict__ csr_src,
                                                  const float* __restrict__ attn_l) {
    int u = xcd_swz(blockIdx.x, gridDim.x);
    agg_unit<1>(u, threadIdx.x, fsb, fdb, hb, offs, cnt, csr_src, attn_l,
                nullptr, nullptr, nullptr, nullptr);
}

// final layer: fused aggregation + graph-sum-pool (no hb write)
__global__ __launch_bounds__(256) void agg_pool_kernel(const unsigned short* __restrict__ fsb,
                                                       const unsigned short* __restrict__ fdb,
                                                       unsigned short* __restrict__ hb,
                                                       const int* __restrict__ offs,
                                                       const int* __restrict__ cnt,
                                                       const int* __restrict__ csr_src,
                                                       const float* __restrict__ attn_l,
                                                       const int* __restrict__ gid,
                                                       float* __restrict__ hg) {
    __shared__ float part[8 * HID];
    __shared__ int gids[8];
    int u = xcd_swz(blockIdx.x, gridDim.x);
    agg_unit<0>(u, threadIdx.x, fsb, fdb, hb, offs, cnt, csr_src, attn_l,
                gid, hg, part, gids);
}

// ---------------- D9: classifier only (pool already folded into agg_pool) ----------------
__global__ __launch_bounds__(256) void cls_kernel(
    const float* __restrict__ hg,
    const float* __restrict__ Wc1, const float* __restrict__ bc1,
    const float* __restrict__ Wc2, const float* __restrict__ bc2,
    const float* __restrict__ Wc3, const float* __restrict__ bc3,
    float* __restrict__ out) {
    __shared__ float xin[HID];
    __shared__ float x1[HID];
    __shared__ float x2[HID / 2];
    int g = blockIdx.x, t = threadIdx.x;
    xin[t] = hg[(size_t)g * HID + t];
    __syncthreads();
    {
        float acc = bc1[t];
        for (int k = 0; k < HID; ++k) acc += xin[k] * Wc1[k * HID + t];
        x1[t] = fmaxf(acc, 0.f);
    }
    __syncthreads();
    if (t < HID / 2) {
        float acc = bc2[t];
        for (int k = 0; k < HID; ++k) acc += x1[k] * Wc2[k * (HID / 2) + t];
        x2[t] = fmaxf(acc, 0.f);
    }
    __syncthreads();
    if (t < OUT_DIM) {
        float acc = bc3[t];
        for (int k = 0; k < HID / 2; ++k) acc += x2[k] * Wc3[k * OUT_DIM + t];
        out[g * OUT_DIM + t] = acc;
    }
}

// ---------------- launch: 10 dispatches (memset + 9 kernels) ----------------
extern "C" void kernel_launch(void* const* d_in, const int* in_sizes, int n_in,
                              void* d_out, int out_size, void* d_ws, size_t ws_size,
                              hipStream_t stream) {
    const float* feature = (const float*)d_in[0];
    const float* W_in   = (const float*)d_in[1];
    const float* b_in   = (const float*)d_in[2];
    const float* W_src  = (const float*)d_in[3];
    const float* b_src  = (const float*)d_in[4];
    const float* W_dst  = (const float*)d_in[5];
    const float* b_dst  = (const float*)d_in[6];
    const float* attn   = (const float*)d_in[7];
    const float* Wc1    = (const float*)d_in[8];
    const float* bc1    = (const float*)d_in[9];
    const float* Wc2    = (const float*)d_in[10];
    const float* bc2    = (const float*)d_in[11];
    const float* Wc3    = (const float*)d_in[12];
    const float* bc3    = (const float*)d_in[13];
    const int* src     = (const int*)d_in[14];
    const int* dst     = (const int*)d_in[15];
    const int* gid     = (const int*)d_in[16];
    float* out = (float*)d_out;

    char* w = (char*)d_ws;
    auto alloc = [&](size_t bytes) -> void* {
        void* p = (void*)w;
        w += (bytes + 255) & ~(size_t)255;
        return p;
    };
    unsigned short* hb  = (unsigned short*)alloc((size_t)N_NODES * HID * 2);  // unified bf16 h
    unsigned short* fsb = (unsigned short*)alloc((size_t)N_NODES * HID * 2);
    unsigned short* fdb = (unsigned short*)alloc((size_t)N_NODES * HID * 2);
    int* cnt     = (int*)alloc((size_t)N_BINS * 4);   // cnt + cglob + hg zeroed by one memset
    int* cglob   = (int*)alloc(4);
    float* hg    = (float*)alloc((size_t)NUM_GRAPHS * HID * 4);
    int* offs    = (int*)alloc((size_t)(N_BINS + 4) * 4);
    int* slot    = (int*)alloc((size_t)N_EDGES * 4);
    int* csr_src = (int*)alloc((size_t)N_EDGES * 4);
    unsigned short* WinT = (unsigned short*)alloc((size_t)IN_DIM * HID * 2);
    unsigned short* WT   = (unsigned short*)alloc((size_t)6 * HID * HID * 2);
    unsigned short* featH = (unsigned short*)alloc((size_t)N_NODES * IN_DIM * 2);
    (void)alloc(4096);  // slack for clamped staging overreach

    // D0: zero cnt + cglob + hg (contiguous region, one memset)
    size_t zlen = (size_t)((char*)offs - (char*)cnt);
    hipMemsetAsync(cnt, 0, zlen, stream);

    // D1: featH cast || LDS-tiled weight transpose || edge-bin count (+slot)
    hipLaunchKernelGGL(prep_count_kernel, dim3(PREP_BLOCKS + COUNT_BLOCKS), dim3(256), 0, stream,
                       feature, W_in, W_src, W_dst, featH, WinT, WT, src, dst, cnt, slot);

    // D2: input-projection GEMM || wide chunk scan (99 blocks, 1 atomic each)
    hipLaunchKernelGGL(gemm0_scan_kernel, dim3(GEMM_TILES + N_CHUNKS), dim3(256), 0, stream,
                       featH, WinT, b_in, hb, cnt, cglob, offs);

    // D3: layer-0 dual GEMM || atomic-free CSR fill
    hipLaunchKernelGGL(gemm1_fill_kernel, dim3(GEMM_TILES + COUNT_BLOCKS), dim3(256), 0, stream,
                       hb, WT, b_src, fsb, WT + 3 * 65536, b_dst, fdb,
                       src, dst, offs, slot, csr_src);

    // D4..D8: agg0, gemm_l1, agg1, gemm_l2, agg_pool(l2)
    for (int l = 0; l < LAYERS; ++l) {
        if (l + 1 < LAYERS) {
            hipLaunchKernelGGL(agg_kernel, dim3(N_NODES / 8), dim3(256), 0, stream,
                               fsb, fdb, hb, offs, cnt, csr_src, attn + (size_t)l * HEADS * DH);
            hipLaunchKernelGGL(gemm_kernel, dim3(313, 2), dim3(256), 0, stream,
                               hb, WT + (size_t)(l + 1) * 65536, b_src + (size_t)(l + 1) * HID, fsb,
                               WT + (size_t)(4 + l) * 65536, b_dst + (size_t)(l + 1) * HID, fdb);
        } else {
            hipLaunchKernelGGL(agg_pool_kernel, dim3(N_NODES / 8), dim3(256), 0, stream,
                               fsb, fdb, hb, offs, cnt, csr_src, attn + (size_t)l * HEADS * DH,
                               gid, hg);
        }
    }

    // D9: classifier
    hipLaunchKernelGGL(cls_kernel, dim3(NUM_GRAPHS), dim3(256), 0, stream,
                       hg, Wc1, bc1, Wc2, bc2, Wc3, bc3, out);
}

// Round 10
// 289.185 us; speedup vs baseline: 1.2634x; 1.0516x over previous
//
#include <hip/hip_runtime.h>
#include <hip/hip_bf16.h>
#include <math.h>

#define N_NODES 20000
#define N_EDGES 320000
#define IN_DIM 128
#define HID 256
#define HEADS 8
#define DH 32
#define LAYERS 3
#define NUM_GRAPHS 64
#define OUT_DIM 10
#define SLOPE 0.2f

// src-bucketed CSR: bucket = src >> 12 (4096 nodes = 2 MB of fsb per bucket)
#define NBKT 5
#define N_BINS (N_NODES * NBKT)      // 100000
#define N_BINS4 (N_BINS / 4)         // 25000

// scan chunks aligned to node boundaries: 1020 bins = 204 nodes * 5 buckets.
#define CHUNK_I4 255                 // int4s per chunk (1020 bins)
#define N_CHUNKS 99                  // ceil(100000 / 1020)

// M32 x N128 tiles: 625 m-tiles x 2 n-tiles = 1250 blocks (4.9/CU vs 2.4 at M64)
#define GEMM_TILES 1250
#define COUNT_BLOCKS 1250            // 320000 / 256

// prep roles: feature cast blocks, LDS-tiled weight-transpose blocks, count blocks
#define CAST_BLOCKS 2500             // 640000 float4s / 256
#define WT_TILES (16 + 192)          // Win: 2x8 tiles; 6 W mats: 4x8 each
#define PREP_BLOCKS (CAST_BLOCKS + WT_TILES)

typedef __bf16 bf16x8 __attribute__((ext_vector_type(8)));
typedef float f32x4 __attribute__((ext_vector_type(4)));

static __device__ __forceinline__ unsigned short f2bfbits(float v) {
    __bf16 b = (__bf16)v;
    return __builtin_bit_cast(unsigned short, b);
}
// unpack 8 bf16 (in a uint4) -> 8 fp32, exact
static __device__ __forceinline__ void unpack8(uint4 u, float* f) {
    unsigned p0 = u.x, p1 = u.y, p2 = u.z, p3 = u.w;
    f[0] = __builtin_bit_cast(float, p0 << 16);
    f[1] = __builtin_bit_cast(float, p0 & 0xffff0000u);
    f[2] = __builtin_bit_cast(float, p1 << 16);
    f[3] = __builtin_bit_cast(float, p1 & 0xffff0000u);
    f[4] = __builtin_bit_cast(float, p2 << 16);
    f[5] = __builtin_bit_cast(float, p2 & 0xffff0000u);
    f[6] = __builtin_bit_cast(float, p3 << 16);
    f[7] = __builtin_bit_cast(float, p3 & 0xffff0000u);
}

// async 16B global->LDS (DMA, wave-uniform LDS base + lane*16)
typedef const __attribute__((address_space(1))) unsigned int* as1_u32p;
typedef __attribute__((address_space(3))) unsigned int* as3_u32p;
static __device__ __forceinline__ void async_cp16(const unsigned short* g, unsigned short* l) {
    __builtin_amdgcn_global_load_lds((as1_u32p)g, (as3_u32p)l, 16, 0, 0);
}

// ---------------- wide scan: block u scans its 1020-bin chunk; base via one atomicAdd ----------------
static __device__ void scans_unit(int u, int t, const int* __restrict__ cnt,
                                  int* __restrict__ cglob, int* __restrict__ offs,
                                  int* si) {
    int idx4 = u * CHUNK_I4 + t;               // t in [0,256); active t < 255
    bool act = (t < CHUNK_I4) && (idx4 < N_BINS4);
    int4 x = make_int4(0, 0, 0, 0);
    if (act) x = ((const int4*)cnt)[idx4];
    int tsum = x.x + x.y + x.z + x.w;
    int v = tsum;
#pragma unroll
    for (int d = 1; d < 64; d <<= 1) {
        int w = __shfl_up(v, d, 64);
        if ((t & 63) >= d) v += w;
    }
    if ((t & 63) == 63) si[4 + (t >> 6)] = v;
    __syncthreads();
    if (t == 0) {
        int S = si[4] + si[5] + si[6] + si[7];
        si[0] = atomicAdd(cglob, S);           // 99 atomics total -- no contention
    }
    __syncthreads();
    int base = si[0];
    int wid = t >> 6;
    int waveoff = 0;
    if (wid > 0) waveoff += si[4];
    if (wid > 1) waveoff += si[5];
    if (wid > 2) waveoff += si[6];
    int ex = base + waveoff + (v - tsum);
    if (act) {
        int4 o;
        o.x = ex; o.y = ex + x.x; o.z = o.y + x.y; o.w = o.z + x.z;
        ((int4*)offs)[idx4] = o;
    }
}

// ---------------- MFMA GEMM tile: M32 x N128, BK=32, regA + LDS-dbuf B ----------------
// Grid doubled vs M64 (1250 blocks = 4.9/CU): fixes block-count quantization
// (626/256 = 2.4 -> 3-phase tail at 4 waves/CU) that capped all prior variants.
// 4 waves tile [2 m-halves x 2 n-halves]: mrow0=(wv>>1)*16, ncb=(wv&1)*64.
template <int DUAL>
static __device__ void gemm_tile(int mt, int nt, int t,
                                 const unsigned short* __restrict__ Ah,
                                 const unsigned short* __restrict__ BT1,
                                 const float* __restrict__ bias1,
                                 unsigned short* __restrict__ O1,
                                 const unsigned short* __restrict__ BT2,
                                 const float* __restrict__ bias2,
                                 unsigned short* __restrict__ O2,
                                 int M, int K, int N,
                                 unsigned short* Bs1P, unsigned short* Bs2P) {
    const int wv = t >> 6, lane = t & 63, quad = lane >> 4, l15 = lane & 15;
    const int m0 = mt * 32, n0 = nt * 128;

    // B staging (byte-identical to proven path; N=128 unchanged)
    const int sB0 = wv * 64 + lane, sB1v = sB0 + 256;
    const int rB0 = sB0 >> 2, cB0 = (sB0 & 3) ^ ((rB0 >> 1) & 3);
    const int rB1 = sB1v >> 2, cB1 = (sB1v & 3) ^ ((rB1 >> 1) & 3);
    const size_t offB0 = (size_t)(n0 + rB0) * K + cB0 * 8;
    const size_t offB1 = (size_t)(n0 + rB1) * K + cB1 * 8;

    auto issueB = [&](int buf, int k0) {
        async_cp16(BT1 + offB0 + k0, Bs1P + buf * 4096 + wv * 512);
        async_cp16(BT1 + offB1 + k0, Bs1P + buf * 4096 + 2048 + wv * 512);
        if (DUAL) {
            async_cp16(BT2 + offB0 + k0, Bs2P + buf * 4096 + wv * 512);
            async_cp16(BT2 + offB1 + k0, Bs2P + buf * 4096 + 2048 + wv * 512);
        }
    };

    const int mrow0 = (wv >> 1) * 16;
    const int ncb = (wv & 1) * 64;

    // single A row pointer per wave (clamped; clamped rows' results discarded)
    int r0 = m0 + mrow0 + l15; if (r0 >= M) r0 = M - 1;
    const unsigned short* Ap0 = Ah + (size_t)r0 * K + quad * 8;

    f32x4 zero = {0.f, 0.f, 0.f, 0.f};
    f32x4 acc1[4], acc2[4];
#pragma unroll
    for (int t4 = 0; t4 < 4; ++t4) { acc1[t4] = zero; acc2[t4] = zero; }

    issueB(0, 0);
    bf16x8 aC0 = __builtin_bit_cast(bf16x8, *(const uint4*)(Ap0));

    int buf = 0;
    for (int k0 = 0; k0 < K; k0 += 32, buf ^= 1) {
        __syncthreads();
        bf16x8 aN0 = aC0;
        if (k0 + 32 < K) {
            issueB(buf ^ 1, k0 + 32);
            aN0 = __builtin_bit_cast(bf16x8, *(const uint4*)(Ap0 + k0 + 32));
        }
#pragma unroll
        for (int t4 = 0; t4 < 4; ++t4) {
            int brow = ncb + t4 * 16 + l15;
            int boff = brow * 32 + ((quad ^ ((brow >> 1) & 3)) << 3);
            bf16x8 b1 = __builtin_bit_cast(bf16x8, *(const uint4*)(Bs1P + buf * 4096 + boff));
            acc1[t4] = __builtin_amdgcn_mfma_f32_16x16x32_bf16(aC0, b1, acc1[t4], 0, 0, 0);
            if (DUAL) {
                bf16x8 b2 = __builtin_bit_cast(bf16x8, *(const uint4*)(Bs2P + buf * 4096 + boff));
                acc2[t4] = __builtin_amdgcn_mfma_f32_16x16x32_bf16(aC0, b2, acc2[t4], 0, 0, 0);
            }
        }
        aC0 = aN0;
    }

    float bia1[4], bia2[4];
#pragma unroll
    for (int t4 = 0; t4 < 4; ++t4) {
        bia1[t4] = bias1[n0 + ncb + t4 * 16 + l15];
        bia2[t4] = DUAL ? bias2[n0 + ncb + t4 * 16 + l15] : 0.f;
    }
#pragma unroll
    for (int t4 = 0; t4 < 4; ++t4) {
        int gn = n0 + ncb + t4 * 16 + l15;
#pragma unroll
        for (int r = 0; r < 4; ++r) {
            int gm = m0 + mrow0 + quad * 4 + r;
            if (gm < M) {
                float v = acc1[t4][r] + bia1[t4];
                O1[(size_t)gm * N + gn] = f2bfbits(v);
                if (DUAL) {
                    float v2 = acc2[t4][r] + bia2[t4];
                    O2[(size_t)gm * N + gn] = f2bfbits(v2);
                }
            }
        }
    }
}

// ---------------- GATv2 aggregation ----------------
// WRITEH=1: write relu(agg+h) back to hb (layers 0,1).
// WRITEH=0: final layer -- skip hb write; block-reduce 8 nodes in LDS and
//           atomicAdd per (graph-run, feature) into hg (gid sorted -> <=8 runs).
template <int WRITEH>
static __device__ void agg_unit(int u, int t,
                                const unsigned short* __restrict__ fsb,
                                const unsigned short* __restrict__ fdb,
                                unsigned short* __restrict__ hb,
                                const int* __restrict__ offs,
                                const int* __restrict__ cnt,
                                const int* __restrict__ csr_src,
                                const float* __restrict__ attn_l,
                                const int* __restrict__ gid,
                                float* __restrict__ hg,
                                float* part, int* gids) {
    int node = u * 8 + (t >> 5);     // grid is exactly 2500*8 = 20000 nodes
    int l32 = t & 31;
    int dbase = l32 * 8;
    int abase = (l32 >> 2) * DH + (l32 & 3) * 8;

    float a[8];
#pragma unroll
    for (int j = 0; j < 8; ++j) a[j] = attn_l[abase + j];

    float fdv[8];
    unpack8(*(const uint4*)(fdb + (size_t)node * HID + dbase), fdv);

    float ssum0 = 0.f, ssum1 = 0.f;
    float acc0[8], acc1[8];
#pragma unroll
    for (int j = 0; j < 8; ++j) { acc0[j] = 0.f; acc1[j] = 0.f; }

    auto procE = [&](uint4 uu, float* acc, float& ssum) {
        float fsv[8];
        unpack8(uu, fsv);
        float p = 0.f;
#pragma unroll
        for (int j = 0; j < 8; ++j) {
            float e = fsv[j] + fdv[j];
            e = fmaxf(e, SLOPE * e);   // leakyrelu (slope<1)
            p += e * a[j];
        }
        p += __shfl_xor(p, 1, 64);
        p += __shfl_xor(p, 2, 64);
        float w = __expf(p);
        ssum += w;
#pragma unroll
        for (int j = 0; j < 8; ++j) acc[j] += w * fsv[j];
    };

    const unsigned short* fsl = fsb + dbase;
    int b0 = node * NBKT;
    int beg = offs[b0];
    int end = offs[b0 + NBKT - 1] + cnt[b0 + NBKT - 1];  // chunk-local contiguity
    int nfull = (end - beg) >> 2;
    const int limit = beg + nfull * 4;

    uint4 cu0, cu1, cu2, cu3;
    int ci0, ci1, ci2, ci3;
    int base = beg + 8;
    bool have = (nfull >= 1);
    bool haveN = (nfull >= 2);
    if (have) {
        int s0 = csr_src[beg], s1 = csr_src[beg + 1];
        int s2 = csr_src[beg + 2], s3 = csr_src[beg + 3];
        if (haveN) {
            ci0 = csr_src[beg + 4]; ci1 = csr_src[beg + 5];
            ci2 = csr_src[beg + 6]; ci3 = csr_src[beg + 7];
        }
        cu0 = *(const uint4*)(fsl + (size_t)s0 * HID);
        cu1 = *(const uint4*)(fsl + (size_t)s1 * HID);
        cu2 = *(const uint4*)(fsl + (size_t)s2 * HID);
        cu3 = *(const uint4*)(fsl + (size_t)s3 * HID);
    }
    while (have) {
        uint4 nu0, nu1, nu2, nu3;
        int ni0, ni1, ni2, ni3;
        if (haveN) {
            nu0 = *(const uint4*)(fsl + (size_t)ci0 * HID);
            nu1 = *(const uint4*)(fsl + (size_t)ci1 * HID);
            nu2 = *(const uint4*)(fsl + (size_t)ci2 * HID);
            nu3 = *(const uint4*)(fsl + (size_t)ci3 * HID);
        }
        bool haveNN = (base + 4 <= limit);
        if (haveNN) {
            ni0 = csr_src[base]; ni1 = csr_src[base + 1];
            ni2 = csr_src[base + 2]; ni3 = csr_src[base + 3];
        }
        base += 4;
        procE(cu0, acc0, ssum0);
        procE(cu1, acc1, ssum1);
        procE(cu2, acc0, ssum0);
        procE(cu3, acc1, ssum1);
        if (haveN) { cu0 = nu0; cu1 = nu1; cu2 = nu2; cu3 = nu3; }
        if (haveNN) { ci0 = ni0; ci1 = ni1; ci2 = ni2; ci3 = ni3; }
        have = haveN; haveN = haveNN;
    }
    for (int idx = limit; idx < end; ++idx) {
        int sv = csr_src[idx];
        procE(*(const uint4*)(fsl + (size_t)sv * HID), acc0, ssum0);
    }

    float ssum = ssum0 + ssum1;
    float acc[8];
#pragma unroll
    for (int j = 0; j < 8; ++j) acc[j] = acc0[j] + acc1[j];

    float inv = ssum > 0.f ? 1.f / ssum : 0.f;
    float hv[8];
    unpack8(*(const uint4*)(hb + (size_t)node * HID + dbase), hv);

    if (WRITEH) {
        unsigned short ob[8];
#pragma unroll
        for (int j = 0; j < 8; ++j) {
            float o = fmaxf(acc[j] * inv + hv[j], 0.f);
            ob[j] = f2bfbits(o);
        }
        *(uint4*)(hb + (size_t)node * HID + dbase) = *(uint4*)ob;
    } else {
        int w = t >> 5;
#pragma unroll
        for (int j = 0; j < 8; ++j)
            part[w * HID + dbase + j] = fmaxf(acc[j] * inv + hv[j], 0.f);
        if (l32 == 0) gids[w] = gid[node];
        __syncthreads();
        // thread t owns feature t; walk the 8 node-rows, flushing on graph change
        float run = 0.f;
        int cur = gids[0];
#pragma unroll
        for (int w2 = 0; w2 < 8; ++w2) {
            int g2 = gids[w2];
            if (g2 != cur) {
                atomicAdd(&hg[(size_t)cur * HID + t], run);
                run = 0.f; cur = g2;
            }
            run += part[w2 * HID + t];
        }
        atomicAdd(&hg[(size_t)cur * HID + t], run);
    }
}

// ---------------- D1: featH cast || LDS-tiled weight transpose || count(+slot) ----------------
__global__ __launch_bounds__(256) void prep_count_kernel(
    const float* __restrict__ feat,
    const float* __restrict__ Win,
    const float* __restrict__ Wsrc,
    const float* __restrict__ Wdst,
    unsigned short* __restrict__ featH,
    unsigned short* __restrict__ WinT,
    unsigned short* __restrict__ WT,
    const int* __restrict__ src,
    const int* __restrict__ dst,
    int* __restrict__ cnt,
    int* __restrict__ slot) {
    __shared__ float Lf[64 * 33];   // 64x32 tile + pad
    int bid = blockIdx.x;
    int t = threadIdx.x;
    if (bid < CAST_BLOCKS) {
        int idx = bid * 256 + t;   // < CAST_N4 by construction (2500*256 = 640000)
        float4 v = ((const float4*)feat)[idx];
        ushort4 o;
        o.x = f2bfbits(v.x); o.y = f2bfbits(v.y);
        o.z = f2bfbits(v.z); o.w = f2bfbits(v.w);
        ((ushort4*)featH)[idx] = o;
    } else if (bid < PREP_BLOCKS) {
        // one 64(k) x 32(n) tile: coalesced f32 row reads -> LDS -> coalesced bf16 col writes
        int b2 = bid - CAST_BLOCKS;
        const float* S;
        unsigned short* D;
        int k0, n0, Kd;
        if (b2 < 16) {                       // W_in: 128(k) x 256(n) -> WinT [256][128]
            S = Win; D = WinT; Kd = IN_DIM;
            k0 = (b2 >> 3) * 64; n0 = (b2 & 7) * 32;
        } else {                             // 6 mats 256x256 -> WT [mat][256][256]
            b2 -= 16;
            int mat = b2 >> 5, tt = b2 & 31;
            S = (mat < 3) ? (Wsrc + (size_t)mat * 65536) : (Wdst + (size_t)(mat - 3) * 65536);
            D = WT + (size_t)mat * 65536; Kd = HID;
            k0 = (tt >> 3) * 64; n0 = (tt & 7) * 32;
        }
        {
            int r = t >> 2, c = (t & 3) * 8;             // read W[k0+r][n0+c .. +8]
            const float* sp = S + (size_t)(k0 + r) * HID + n0 + c;
            float4 v0 = *(const float4*)(sp);
            float4 v1 = *(const float4*)(sp + 4);
            float* lp = Lf + r * 33 + c;
            lp[0] = v0.x; lp[1] = v0.y; lp[2] = v0.z; lp[3] = v0.w;
            lp[4] = v1.x; lp[5] = v1.y; lp[6] = v1.z; lp[7] = v1.w;
        }
        __syncthreads();
        {
            int nn = t >> 3, kk = (t & 7) * 8;           // write D[n0+nn][k0+kk .. +8]
            unsigned short ob[8];
#pragma unroll
            for (int j = 0; j < 8; ++j) ob[j] = f2bfbits(Lf[(kk + j) * 33 + nn]);
            *(uint4*)(D + (size_t)(n0 + nn) * Kd + k0 + kk) = *(uint4*)ob;
        }
    } else {
        int e = (bid - PREP_BLOCKS) * 256 + t;
        if (e < N_EDGES) {
            int bin = dst[e] * NBKT + (src[e] >> 12);
            slot[e] = atomicAdd(&cnt[bin], 1);   // slot within bin, fixed at count time
        }
    }
}

// ---------------- D2: input-projection GEMM || wide chunk scan ----------------
__global__ __launch_bounds__(256, 4) void gemm0_scan_kernel(
    const unsigned short* __restrict__ featH, const unsigned short* __restrict__ WinT,
    const float* __restrict__ b_in, unsigned short* __restrict__ hb,
    const int* __restrict__ cnt, int* __restrict__ cglob,
    int* __restrict__ offs) {
    __shared__ __align__(16) unsigned short smem[8192];
    int bid = blockIdx.x;
    if (bid < GEMM_TILES) {
        gemm_tile<0>(bid >> 1, bid & 1, threadIdx.x, featH, WinT, b_in, hb,
                     (const unsigned short*)nullptr, (const float*)nullptr,
                     (unsigned short*)nullptr, N_NODES, IN_DIM, HID,
                     smem, smem);
    } else {
        scans_unit(bid - GEMM_TILES, threadIdx.x, cnt, cglob, offs,
                   (int*)(void*)smem);
    }
}

// ---------------- D3: layer-0 dual GEMM || atomic-free CSR fill ----------------
__global__ __launch_bounds__(256, 4) void gemm1_fill_kernel(
    const unsigned short* __restrict__ hb,
    const unsigned short* __restrict__ WTs, const float* __restrict__ bs,
    unsigned short* __restrict__ fsb,
    const unsigned short* __restrict__ WTd, const float* __restrict__ bd,
    unsigned short* __restrict__ fdb,
    const int* __restrict__ src, const int* __restrict__ dst,
    const int* __restrict__ offs, const int* __restrict__ slot,
    int* __restrict__ csr_src) {
    __shared__ __align__(16) unsigned short smem[16384];
    int bid = blockIdx.x;
    if (bid < GEMM_TILES) {
        gemm_tile<1>(bid >> 1, bid & 1, threadIdx.x, hb, WTs, bs, fsb, WTd, bd, fdb,
                     N_NODES, HID, HID, smem, smem + 8192);
    } else {
        int e = (bid - GEMM_TILES) * 256 + threadIdx.x;
        if (e < N_EDGES) {
            int sv = src[e];
            int bin = dst[e] * NBKT + (sv >> 12);
            csr_src[offs[bin] + slot[e]] = sv;   // no atomic: slot fixed in D1
        }
    }
}

// ---------------- standalone dual GEMM (layers 1,2) ----------------
__global__ __launch_bounds__(256, 4) void gemm_kernel(
    const unsigned short* __restrict__ Ah,
    const unsigned short* __restrict__ BT1, const float* __restrict__ bias1,
    unsigned short* __restrict__ O1,
    const unsigned short* __restrict__ BT2, const float* __restrict__ bias2,
    unsigned short* __restrict__ O2) {
    __shared__ __align__(16) unsigned short smem[16384];
    gemm_tile<1>(blockIdx.x, blockIdx.y, threadIdx.x, Ah, BT1, bias1, O1,
                 BT2, bias2, O2, N_NODES, HID, HID, smem, smem + 8192);
}

// ---------------- aggregation dispatches (XCD-aware bijective block swizzle, T1/m204) ----------------
static __device__ __forceinline__ int xcd_swz(int b, int nwg) {
    int q = nwg >> 3, r = nwg & 7;
    int xcd = b & 7, idx = b >> 3;
    return (xcd < r) ? xcd * (q + 1) + idx
                     : r * (q + 1) + (xcd - r) * q + idx;
}

__global__ __launch_bounds__(256) void agg_kernel(const unsigned short* __restrict__ fsb,
                                                  const unsigned short* __restrict__ fdb,
                                                  unsigned short* __restrict__ hb,
                                                  const int* __restrict__ offs,
                                                  const int* __restrict__ cnt,
                                                  const int* __restrict__ csr_src,
                                                  const float* __restrict__ attn_l) {
    int u = xcd_swz(blockIdx.x, gridDim.x);
    agg_unit<1>(u, threadIdx.x, fsb, fdb, hb, offs, cnt, csr_src, attn_l,
                nullptr, nullptr, nullptr, nullptr);
}

// final layer: fused aggregation + graph-sum-pool (no hb write)
__global__ __launch_bounds__(256) void agg_pool_kernel(const unsigned short* __restrict__ fsb,
                                                       const unsigned short* __restrict__ fdb,
                                                       unsigned short* __restrict__ hb,
                                                       const int* __restrict__ offs,
                                                       const int* __restrict__ cnt,
                                                       const int* __restrict__ csr_src,
                                                       const float* __restrict__ attn_l,
                                                       const int* __restrict__ gid,
                                                       float* __restrict__ hg) {
    __shared__ float part[8 * HID];
    __shared__ int gids[8];
    int u = xcd_swz(blockIdx.x, gridDim.x);
    agg_unit<0>(u, threadIdx.x, fsb, fdb, hb, offs, cnt, csr_src, attn_l,
                gid, hg, part, gids);
}

// ---------------- D9: classifier only (pool already folded into agg_pool) ----------------
__global__ __launch_bounds__(256) void cls_kernel(
    const float* __restrict__ hg,
    const float* __restrict__ Wc1, const float* __restrict__ bc1,
    const float* __restrict__ Wc2, const float* __restrict__ bc2,
    const float* __restrict__ Wc3, const float* __restrict__ bc3,
    float* __restrict__ out) {
    __shared__ float xin[HID];
    __shared__ float x1[HID];
    __shared__ float x2[HID / 2];
    int g = blockIdx.x, t = threadIdx.x;
    xin[t] = hg[(size_t)g * HID + t];
    __syncthreads();
    {
        float acc = bc1[t];
        for (int k = 0; k < HID; ++k) acc += xin[k] * Wc1[k * HID + t];
        x1[t] = fmaxf(acc, 0.f);
    }
    __syncthreads();
    if (t < HID / 2) {
        float acc = bc2[t];
        for (int k = 0; k < HID; ++k) acc += x1[k] * Wc2[k * (HID / 2) + t];
        x2[t] = fmaxf(acc, 0.f);
    }
    __syncthreads();
    if (t < OUT_DIM) {
        float acc = bc3[t];
        for (int k = 0; k < HID / 2; ++k) acc += x2[k] * Wc3[k * OUT_DIM + t];
        out[g * OUT_DIM + t] = acc;
    }
}

// ---------------- launch: 10 dispatches (memset + 9 kernels) ----------------
extern "C" void kernel_launch(void* const* d_in, const int* in_sizes, int n_in,
                              void* d_out, int out_size, void* d_ws, size_t ws_size,
                              hipStream_t stream) {
    const float* feature = (const float*)d_in[0];
    const float* W_in   = (const float*)d_in[1];
    const float* b_in   = (const float*)d_in[2];
    const float* W_src  = (const float*)d_in[3];
    const float* b_src  = (const float*)d_in[4];
    const float* W_dst  = (const float*)d_in[5];
    const float* b_dst  = (const float*)d_in[6];
    const float* attn   = (const float*)d_in[7];
    const float* Wc1    = (const float*)d_in[8];
    const float* bc1    = (const float*)d_in[9];
    const float* Wc2    = (const float*)d_in[10];
    const float* bc2    = (const float*)d_in[11];
    const float* Wc3    = (const float*)d_in[12];
    const float* bc3    = (const float*)d_in[13];
    const int* src     = (const int*)d_in[14];
    const int* dst     = (const int*)d_in[15];
    const int* gid     = (const int*)d_in[16];
    float* out = (float*)d_out;

    char* w = (char*)d_ws;
    auto alloc = [&](size_t bytes) -> void* {
        void* p = (void*)w;
        w += (bytes + 255) & ~(size_t)255;
        return p;
    };
    unsigned short* hb  = (unsigned short*)alloc((size_t)N_NODES * HID * 2);  // unified bf16 h
    unsigned short* fsb = (unsigned short*)alloc((size_t)N_NODES * HID * 2);
    unsigned short* fdb = (unsigned short*)alloc((size_t)N_NODES * HID * 2);
    int* cnt     = (int*)alloc((size_t)N_BINS * 4);   // cnt + cglob + hg zeroed by one memset
    int* cglob   = (int*)alloc(4);
    float* hg    = (float*)alloc((size_t)NUM_GRAPHS * HID * 4);
    int* offs    = (int*)alloc((size_t)(N_BINS + 4) * 4);
    int* slot    = (int*)alloc((size_t)N_EDGES * 4);
    int* csr_src = (int*)alloc((size_t)N_EDGES * 4);
    unsigned short* WinT = (unsigned short*)alloc((size_t)IN_DIM * HID * 2);
    unsigned short* WT   = (unsigned short*)alloc((size_t)6 * HID * HID * 2);
    unsigned short* featH = (unsigned short*)alloc((size_t)N_NODES * IN_DIM * 2);
    (void)alloc(4096);  // slack for clamped staging overreach

    // D0: zero cnt + cglob + hg (contiguous region, one memset)
    size_t zlen = (size_t)((char*)offs - (char*)cnt);
    hipMemsetAsync(cnt, 0, zlen, stream);

    // D1: featH cast || LDS-tiled weight transpose || edge-bin count (+slot)
    hipLaunchKernelGGL(prep_count_kernel, dim3(PREP_BLOCKS + COUNT_BLOCKS), dim3(256), 0, stream,
                       feature, W_in, W_src, W_dst, featH, WinT, WT, src, dst, cnt, slot);

    // D2: input-projection GEMM || wide chunk scan (99 blocks, 1 atomic each)
    hipLaunchKernelGGL(gemm0_scan_kernel, dim3(GEMM_TILES + N_CHUNKS), dim3(256), 0, stream,
                       featH, WinT, b_in, hb, cnt, cglob, offs);

    // D3: layer-0 dual GEMM || atomic-free CSR fill
    hipLaunchKernelGGL(gemm1_fill_kernel, dim3(GEMM_TILES + COUNT_BLOCKS), dim3(256), 0, stream,
                       hb, WT, b_src, fsb, WT + 3 * 65536, b_dst, fdb,
                       src, dst, offs, slot, csr_src);

    // D4..D8: agg0, gemm_l1, agg1, gemm_l2, agg_pool(l2)
    for (int l = 0; l < LAYERS; ++l) {
        if (l + 1 < LAYERS) {
            hipLaunchKernelGGL(agg_kernel, dim3(N_NODES / 8), dim3(256), 0, stream,
                               fsb, fdb, hb, offs, cnt, csr_src, attn + (size_t)l * HEADS * DH);
            hipLaunchKernelGGL(gemm_kernel, dim3(625, 2), dim3(256), 0, stream,
                               hb, WT + (size_t)(l + 1) * 65536, b_src + (size_t)(l + 1) * HID, fsb,
                               WT + (size_t)(4 + l) * 65536, b_dst + (size_t)(l + 1) * HID, fdb);
        } else {
            hipLaunchKernelGGL(agg_pool_kernel, dim3(N_NODES / 8), dim3(256), 0, stream,
                               fsb, fdb, hb, offs, cnt, csr_src, attn + (size_t)l * HEADS * DH,
                               gid, hg);
        }
    }

    // D9: classifier
    hipLaunchKernelGGL(cls_kernel, dim3(NUM_GRAPHS), dim3(256), 0, stream,
                       hg, Wc1, bc1, Wc2, bc2, Wc3, bc3, out);
}

// Round 12
// 287.219 us; speedup vs baseline: 1.2721x; 1.0068x over previous
//
#include <hip/hip_runtime.h>
#include <hip/hip_bf16.h>
#include <math.h>

#define N_NODES 20000
#define N_EDGES 320000
#define IN_DIM 128
#define HID 256
#define HEADS 8
#define DH 32
#define LAYERS 3
#define NUM_GRAPHS 64
#define OUT_DIM 10
#define SLOPE 0.2f

// src-bucketed CSR: bucket = src >> 12 (4096 nodes = 2 MB of fsb per bucket)
#define NBKT 5
#define N_BINS (N_NODES * NBKT)      // 100000
#define N_BINS4 (N_BINS / 4)         // 25000

// scan chunks aligned to node boundaries: 1020 bins = 204 nodes * 5 buckets.
#define CHUNK_I4 255                 // int4s per chunk (1020 bins)
#define N_CHUNKS 99                  // ceil(100000 / 1020)

// M32 x N128 tiles: 625 m-tiles x 2 n-tiles = 1250 blocks (R10 proven)
#define GEMM_TILES 1250
#define COUNT_BLOCKS 1250            // 320000 / 256

// prep roles: LDS-tiled weight transposes only (featH cast removed: gemm0
// reads f32 feature directly, converting in-register -- bit-identical bf16)
#define PREP_BLOCKS (16 + 192)       // Win: 2x8 tiles; 6 W mats: 4x8 each

typedef __bf16 bf16x8 __attribute__((ext_vector_type(8)));
typedef float f32x4 __attribute__((ext_vector_type(4)));

static __device__ __forceinline__ unsigned short f2bfbits(float v) {
    __bf16 b = (__bf16)v;
    return __builtin_bit_cast(unsigned short, b);
}
// unpack 8 bf16 (in a uint4) -> 8 fp32, exact
static __device__ __forceinline__ void unpack8(uint4 u, float* f) {
    unsigned p0 = u.x, p1 = u.y, p2 = u.z, p3 = u.w;
    f[0] = __builtin_bit_cast(float, p0 << 16);
    f[1] = __builtin_bit_cast(float, p0 & 0xffff0000u);
    f[2] = __builtin_bit_cast(float, p1 << 16);
    f[3] = __builtin_bit_cast(float, p1 & 0xffff0000u);
    f[4] = __builtin_bit_cast(float, p2 << 16);
    f[5] = __builtin_bit_cast(float, p2 & 0xffff0000u);
    f[6] = __builtin_bit_cast(float, p3 << 16);
    f[7] = __builtin_bit_cast(float, p3 & 0xffff0000u);
}

// async 16B global->LDS (DMA, wave-uniform LDS base + lane*16)
typedef const __attribute__((address_space(1))) unsigned int* as1_u32p;
typedef __attribute__((address_space(3))) unsigned int* as3_u32p;
static __device__ __forceinline__ void async_cp16(const unsigned short* g, unsigned short* l) {
    __builtin_amdgcn_global_load_lds((as1_u32p)g, (as3_u32p)l, 16, 0, 0);
}

// ---------------- wide scan: block u scans its 1020-bin chunk; base via one atomicAdd ----------------
static __device__ void scans_unit(int u, int t, const int* __restrict__ cnt,
                                  int* __restrict__ cglob, int* __restrict__ offs,
                                  int* si) {
    int idx4 = u * CHUNK_I4 + t;               // t in [0,256); active t < 255
    bool act = (t < CHUNK_I4) && (idx4 < N_BINS4);
    int4 x = make_int4(0, 0, 0, 0);
    if (act) x = ((const int4*)cnt)[idx4];
    int tsum = x.x + x.y + x.z + x.w;
    int v = tsum;
#pragma unroll
    for (int d = 1; d < 64; d <<= 1) {
        int w = __shfl_up(v, d, 64);
        if ((t & 63) >= d) v += w;
    }
    if ((t & 63) == 63) si[4 + (t >> 6)] = v;
    __syncthreads();
    if (t == 0) {
        int S = si[4] + si[5] + si[6] + si[7];
        si[0] = atomicAdd(cglob, S);           // 99 atomics total -- no contention
    }
    __syncthreads();
    int base = si[0];
    int wid = t >> 6;
    int waveoff = 0;
    if (wid > 0) waveoff += si[4];
    if (wid > 1) waveoff += si[5];
    if (wid > 2) waveoff += si[6];
    int ex = base + waveoff + (v - tsum);
    if (act) {
        int4 o;
        o.x = ex; o.y = ex + x.x; o.z = o.y + x.y; o.w = o.z + x.z;
        ((int4*)offs)[idx4] = o;
    }
}

// ---------------- MFMA GEMM tile: M32 x N128, BK=32, regA + LDS-dbuf B (R10 proven) ----------------
// AF32=1: A is f32, converted in-register with the same RNE cast the old featH
// cast kernel used -> MFMA sees bit-identical bf16 inputs (hb unchanged).
template <int DUAL, int AF32>
static __device__ void gemm_tile(int mt, int nt, int t,
                                 const void* __restrict__ Av,
                                 const unsigned short* __restrict__ BT1,
                                 const float* __restrict__ bias1,
                                 unsigned short* __restrict__ O1,
                                 const unsigned short* __restrict__ BT2,
                                 const float* __restrict__ bias2,
                                 unsigned short* __restrict__ O2,
                                 int M, int K, int N,
                                 unsigned short* Bs1P, unsigned short* Bs2P) {
    const int wv = t >> 6, lane = t & 63, quad = lane >> 4, l15 = lane & 15;
    const int m0 = mt * 32, n0 = nt * 128;

    // B staging (byte-identical to proven path; N=128 unchanged)
    const int sB0 = wv * 64 + lane, sB1v = sB0 + 256;
    const int rB0 = sB0 >> 2, cB0 = (sB0 & 3) ^ ((rB0 >> 1) & 3);
    const int rB1 = sB1v >> 2, cB1 = (sB1v & 3) ^ ((rB1 >> 1) & 3);
    const size_t offB0 = (size_t)(n0 + rB0) * K + cB0 * 8;
    const size_t offB1 = (size_t)(n0 + rB1) * K + cB1 * 8;

    auto issueB = [&](int buf, int k0) {
        async_cp16(BT1 + offB0 + k0, Bs1P + buf * 4096 + wv * 512);
        async_cp16(BT1 + offB1 + k0, Bs1P + buf * 4096 + 2048 + wv * 512);
        if (DUAL) {
            async_cp16(BT2 + offB0 + k0, Bs2P + buf * 4096 + wv * 512);
            async_cp16(BT2 + offB1 + k0, Bs2P + buf * 4096 + 2048 + wv * 512);
        }
    };

    const int mrow0 = (wv >> 1) * 16;
    const int ncb = (wv & 1) * 64;

    // single A row pointer per wave (clamped; clamped rows' results discarded)
    int r0 = m0 + mrow0 + l15; if (r0 >= M) r0 = M - 1;
    const unsigned short* Ap0h = (const unsigned short*)Av + (size_t)r0 * K + quad * 8;
    const float* Ap0f = (const float*)Av + (size_t)r0 * K + quad * 8;

    auto ldA = [&](int k0) -> bf16x8 {
        if (AF32) {
            float4 v0 = *(const float4*)(Ap0f + k0);
            float4 v1 = *(const float4*)(Ap0f + k0 + 4);
            unsigned short u[8];
            u[0] = f2bfbits(v0.x); u[1] = f2bfbits(v0.y);
            u[2] = f2bfbits(v0.z); u[3] = f2bfbits(v0.w);
            u[4] = f2bfbits(v1.x); u[5] = f2bfbits(v1.y);
            u[6] = f2bfbits(v1.z); u[7] = f2bfbits(v1.w);
            return __builtin_bit_cast(bf16x8, *(uint4*)u);
        } else {
            return __builtin_bit_cast(bf16x8, *(const uint4*)(Ap0h + k0));
        }
    };

    f32x4 zero = {0.f, 0.f, 0.f, 0.f};
    f32x4 acc1[4], acc2[4];
#pragma unroll
    for (int t4 = 0; t4 < 4; ++t4) { acc1[t4] = zero; acc2[t4] = zero; }

    issueB(0, 0);
    bf16x8 aC0 = ldA(0);

    int buf = 0;
    for (int k0 = 0; k0 < K; k0 += 32, buf ^= 1) {
        __syncthreads();
        bf16x8 aN0 = aC0;
        if (k0 + 32 < K) {
            issueB(buf ^ 1, k0 + 32);
            aN0 = ldA(k0 + 32);
        }
#pragma unroll
        for (int t4 = 0; t4 < 4; ++t4) {
            int brow = ncb + t4 * 16 + l15;
            int boff = brow * 32 + ((quad ^ ((brow >> 1) & 3)) << 3);
            bf16x8 b1 = __builtin_bit_cast(bf16x8, *(const uint4*)(Bs1P + buf * 4096 + boff));
            acc1[t4] = __builtin_amdgcn_mfma_f32_16x16x32_bf16(aC0, b1, acc1[t4], 0, 0, 0);
            if (DUAL) {
                bf16x8 b2 = __builtin_bit_cast(bf16x8, *(const uint4*)(Bs2P + buf * 4096 + boff));
                acc2[t4] = __builtin_amdgcn_mfma_f32_16x16x32_bf16(aC0, b2, acc2[t4], 0, 0, 0);
            }
        }
        aC0 = aN0;
    }

    float bia1[4], bia2[4];
#pragma unroll
    for (int t4 = 0; t4 < 4; ++t4) {
        bia1[t4] = bias1[n0 + ncb + t4 * 16 + l15];
        bia2[t4] = DUAL ? bias2[n0 + ncb + t4 * 16 + l15] : 0.f;
    }
#pragma unroll
    for (int t4 = 0; t4 < 4; ++t4) {
        int gn = n0 + ncb + t4 * 16 + l15;
#pragma unroll
        for (int r = 0; r < 4; ++r) {
            int gm = m0 + mrow0 + quad * 4 + r;
            if (gm < M) {
                float v = acc1[t4][r] + bia1[t4];
                O1[(size_t)gm * N + gn] = f2bfbits(v);
                if (DUAL) {
                    float v2 = acc2[t4][r] + bia2[t4];
                    O2[(size_t)gm * N + gn] = f2bfbits(v2);
                }
            }
        }
    }
}

// ---------------- GATv2 aggregation (R10 proven) ----------------
// WRITEH=1: write relu(agg+h) back to hb (layers 0,1).
// WRITEH=0: final layer -- skip hb write; block-reduce 8 nodes in LDS and
//           atomicAdd per (graph-run, feature) into hg (gid sorted -> <=8 runs).
template <int WRITEH>
static __device__ void agg_unit(int u, int t,
                                const unsigned short* __restrict__ fsb,
                                const unsigned short* __restrict__ fdb,
                                unsigned short* __restrict__ hb,
                                const int* __restrict__ offs,
                                const int* __restrict__ cnt,
                                const int* __restrict__ csr_src,
                                const float* __restrict__ attn_l,
                                const int* __restrict__ gid,
                                float* __restrict__ hg,
                                float* part, int* gids) {
    int node = u * 8 + (t >> 5);     // grid is exactly 2500*8 = 20000 nodes
    int l32 = t & 31;
    int dbase = l32 * 8;
    int abase = (l32 >> 2) * DH + (l32 & 3) * 8;

    float a[8];
#pragma unroll
    for (int j = 0; j < 8; ++j) a[j] = attn_l[abase + j];

    float fdv[8];
    unpack8(*(const uint4*)(fdb + (size_t)node * HID + dbase), fdv);

    float ssum0 = 0.f, ssum1 = 0.f;
    float acc0[8], acc1[8];
#pragma unroll
    for (int j = 0; j < 8; ++j) { acc0[j] = 0.f; acc1[j] = 0.f; }

    auto procE = [&](uint4 uu, float* acc, float& ssum) {
        float fsv[8];
        unpack8(uu, fsv);
        float p = 0.f;
#pragma unroll
        for (int j = 0; j < 8; ++j) {
            float e = fsv[j] + fdv[j];
            e = fmaxf(e, SLOPE * e);   // leakyrelu (slope<1)
            p += e * a[j];
        }
        p += __shfl_xor(p, 1, 64);
        p += __shfl_xor(p, 2, 64);
        float w = __expf(p);
        ssum += w;
#pragma unroll
        for (int j = 0; j < 8; ++j) acc[j] += w * fsv[j];
    };

    const unsigned short* fsl = fsb + dbase;
    int b0 = node * NBKT;
    int beg = offs[b0];
    int end = offs[b0 + NBKT - 1] + cnt[b0 + NBKT - 1];  // chunk-local contiguity
    int nfull = (end - beg) >> 2;
    const int limit = beg + nfull * 4;

    uint4 cu0, cu1, cu2, cu3;
    int ci0, ci1, ci2, ci3;
    int base = beg + 8;
    bool have = (nfull >= 1);
    bool haveN = (nfull >= 2);
    if (have) {
        int s0 = csr_src[beg], s1 = csr_src[beg + 1];
        int s2 = csr_src[beg + 2], s3 = csr_src[beg + 3];
        if (haveN) {
            ci0 = csr_src[beg + 4]; ci1 = csr_src[beg + 5];
            ci2 = csr_src[beg + 6]; ci3 = csr_src[beg + 7];
        }
        cu0 = *(const uint4*)(fsl + (size_t)s0 * HID);
        cu1 = *(const uint4*)(fsl + (size_t)s1 * HID);
        cu2 = *(const uint4*)(fsl + (size_t)s2 * HID);
        cu3 = *(const uint4*)(fsl + (size_t)s3 * HID);
    }
    while (have) {
        uint4 nu0, nu1, nu2, nu3;
        int ni0, ni1, ni2, ni3;
        if (haveN) {
            nu0 = *(const uint4*)(fsl + (size_t)ci0 * HID);
            nu1 = *(const uint4*)(fsl + (size_t)ci1 * HID);
            nu2 = *(const uint4*)(fsl + (size_t)ci2 * HID);
            nu3 = *(const uint4*)(fsl + (size_t)ci3 * HID);
        }
        bool haveNN = (base + 4 <= limit);
        if (haveNN) {
            ni0 = csr_src[base]; ni1 = csr_src[base + 1];
            ni2 = csr_src[base + 2]; ni3 = csr_src[base + 3];
        }
        base += 4;
        procE(cu0, acc0, ssum0);
        procE(cu1, acc1, ssum1);
        procE(cu2, acc0, ssum0);
        procE(cu3, acc1, ssum1);
        if (haveN) { cu0 = nu0; cu1 = nu1; cu2 = nu2; cu3 = nu3; }
        if (haveNN) { ci0 = ni0; ci1 = ni1; ci2 = ni2; ci3 = ni3; }
        have = haveN; haveN = haveNN;
    }
    for (int idx = limit; idx < end; ++idx) {
        int sv = csr_src[idx];
        procE(*(const uint4*)(fsl + (size_t)sv * HID), acc0, ssum0);
    }

    float ssum = ssum0 + ssum1;
    float acc[8];
#pragma unroll
    for (int j = 0; j < 8; ++j) acc[j] = acc0[j] + acc1[j];

    float inv = ssum > 0.f ? 1.f / ssum : 0.f;
    float hv[8];
    unpack8(*(const uint4*)(hb + (size_t)node * HID + dbase), hv);

    if (WRITEH) {
        unsigned short ob[8];
#pragma unroll
        for (int j = 0; j < 8; ++j) {
            float o = fmaxf(acc[j] * inv + hv[j], 0.f);
            ob[j] = f2bfbits(o);
        }
        *(uint4*)(hb + (size_t)node * HID + dbase) = *(uint4*)ob;
    } else {
        int w = t >> 5;
#pragma unroll
        for (int j = 0; j < 8; ++j)
            part[w * HID + dbase + j] = fmaxf(acc[j] * inv + hv[j], 0.f);
        if (l32 == 0) gids[w] = gid[node];
        __syncthreads();
        // thread t owns feature t; walk the 8 node-rows, flushing on graph change
        float run = 0.f;
        int cur = gids[0];
#pragma unroll
        for (int w2 = 0; w2 < 8; ++w2) {
            int g2 = gids[w2];
            if (g2 != cur) {
                atomicAdd(&hg[(size_t)cur * HID + t], run);
                run = 0.f; cur = g2;
            }
            run += part[w2 * HID + t];
        }
        atomicAdd(&hg[(size_t)cur * HID + t], run);
    }
}

// ---------------- D1: LDS-tiled weight transpose || count(+slot) ----------------
__global__ __launch_bounds__(256) void prep_count_kernel(
    const float* __restrict__ Win,
    const float* __restrict__ Wsrc,
    const float* __restrict__ Wdst,
    unsigned short* __restrict__ WinT,
    unsigned short* __restrict__ WT,
    const int* __restrict__ src,
    const int* __restrict__ dst,
    int* __restrict__ cnt,
    int* __restrict__ slot) {
    __shared__ float Lf[64 * 33];   // 64x32 tile + pad
    int bid = blockIdx.x;
    int t = threadIdx.x;
    if (bid < PREP_BLOCKS) {
        // one 64(k) x 32(n) tile: coalesced f32 row reads -> LDS -> coalesced bf16 col writes
        int b2 = bid;
        const float* S;
        unsigned short* D;
        int k0, n0, Kd;
        if (b2 < 16) {                       // W_in: 128(k) x 256(n) -> WinT [256][128]
            S = Win; D = WinT; Kd = IN_DIM;
            k0 = (b2 >> 3) * 64; n0 = (b2 & 7) * 32;
        } else {                             // 6 mats 256x256 -> WT [mat][256][256]
            b2 -= 16;
            int mat = b2 >> 5, tt = b2 & 31;
            S = (mat < 3) ? (Wsrc + (size_t)mat * 65536) : (Wdst + (size_t)(mat - 3) * 65536);
            D = WT + (size_t)mat * 65536; Kd = HID;
            k0 = (tt >> 3) * 64; n0 = (tt & 7) * 32;
        }
        {
            int r = t >> 2, c = (t & 3) * 8;             // read W[k0+r][n0+c .. +8]
            const float* sp = S + (size_t)(k0 + r) * HID + n0 + c;
            float4 v0 = *(const float4*)(sp);
            float4 v1 = *(const float4*)(sp + 4);
            float* lp = Lf + r * 33 + c;
            lp[0] = v0.x; lp[1] = v0.y; lp[2] = v0.z; lp[3] = v0.w;
            lp[4] = v1.x; lp[5] = v1.y; lp[6] = v1.z; lp[7] = v1.w;
        }
        __syncthreads();
        {
            int nn = t >> 3, kk = (t & 7) * 8;           // write D[n0+nn][k0+kk .. +8]
            unsigned short ob[8];
#pragma unroll
            for (int j = 0; j < 8; ++j) ob[j] = f2bfbits(Lf[(kk + j) * 33 + nn]);
            *(uint4*)(D + (size_t)(n0 + nn) * Kd + k0 + kk) = *(uint4*)ob;
        }
    } else {
        int e = (bid - PREP_BLOCKS) * 256 + t;
        if (e < N_EDGES) {
            int bin = dst[e] * NBKT + (src[e] >> 12);
            slot[e] = atomicAdd(&cnt[bin], 1);   // slot within bin, fixed at count time
        }
    }
}

// ---------------- D2: input-projection GEMM (f32 A direct) || wide chunk scan ----------------
__global__ __launch_bounds__(256, 4) void gemm0_scan_kernel(
    const float* __restrict__ feat, const unsigned short* __restrict__ WinT,
    const float* __restrict__ b_in, unsigned short* __restrict__ hb,
    const int* __restrict__ cnt, int* __restrict__ cglob,
    int* __restrict__ offs) {
    __shared__ __align__(16) unsigned short smem[8192];
    int bid = blockIdx.x;
    if (bid < GEMM_TILES) {
        gemm_tile<0, 1>(bid >> 1, bid & 1, threadIdx.x, feat, WinT, b_in, hb,
                        (const unsigned short*)nullptr, (const float*)nullptr,
                        (unsigned short*)nullptr, N_NODES, IN_DIM, HID,
                        smem, smem);
    } else {
        scans_unit(bid - GEMM_TILES, threadIdx.x, cnt, cglob, offs,
                   (int*)(void*)smem);
    }
}

// ---------------- D3: layer-0 dual GEMM || atomic-free CSR fill ----------------
__global__ __launch_bounds__(256, 4) void gemm1_fill_kernel(
    const unsigned short* __restrict__ hb,
    const unsigned short* __restrict__ WTs, const float* __restrict__ bs,
    unsigned short* __restrict__ fsb,
    const unsigned short* __restrict__ WTd, const float* __restrict__ bd,
    unsigned short* __restrict__ fdb,
    const int* __restrict__ src, const int* __restrict__ dst,
    const int* __restrict__ offs, const int* __restrict__ slot,
    int* __restrict__ csr_src) {
    __shared__ __align__(16) unsigned short smem[16384];
    int bid = blockIdx.x;
    if (bid < GEMM_TILES) {
        gemm_tile<1, 0>(bid >> 1, bid & 1, threadIdx.x, hb, WTs, bs, fsb, WTd, bd, fdb,
                        N_NODES, HID, HID, smem, smem + 8192);
    } else {
        int e = (bid - GEMM_TILES) * 256 + threadIdx.x;
        if (e < N_EDGES) {
            int sv = src[e];
            int bin = dst[e] * NBKT + (sv >> 12);
            csr_src[offs[bin] + slot[e]] = sv;   // no atomic: slot fixed in D1
        }
    }
}

// ---------------- standalone dual GEMM (layers 1,2) ----------------
__global__ __launch_bounds__(256, 4) void gemm_kernel(
    const unsigned short* __restrict__ Ah,
    const unsigned short* __restrict__ BT1, const float* __restrict__ bias1,
    unsigned short* __restrict__ O1,
    const unsigned short* __restrict__ BT2, const float* __restrict__ bias2,
    unsigned short* __restrict__ O2) {
    __shared__ __align__(16) unsigned short smem[16384];
    gemm_tile<1, 0>(blockIdx.x, blockIdx.y, threadIdx.x, Ah, BT1, bias1, O1,
                    BT2, bias2, O2, N_NODES, HID, HID, smem, smem + 8192);
}

// ---------------- aggregation dispatches (XCD-aware bijective block swizzle, T1/m204) ----------------
static __device__ __forceinline__ int xcd_swz(int b, int nwg) {
    int q = nwg >> 3, r = nwg & 7;
    int xcd = b & 7, idx = b >> 3;
    return (xcd < r) ? xcd * (q + 1) + idx
                     : r * (q + 1) + (xcd - r) * q + idx;
}

__global__ __launch_bounds__(256) void agg_kernel(const unsigned short* __restrict__ fsb,
                                                  const unsigned short* __restrict__ fdb,
                                                  unsigned short* __restrict__ hb,
                                                  const int* __restrict__ offs,
                                                  const int* __restrict__ cnt,
                                                  const int* __restrict__ csr_src,
                                                  const float* __restrict__ attn_l) {
    int u = xcd_swz(blockIdx.x, gridDim.x);
    agg_unit<1>(u, threadIdx.x, fsb, fdb, hb, offs, cnt, csr_src, attn_l,
                nullptr, nullptr, nullptr, nullptr);
}

// final layer: fused aggregation + graph-sum-pool (no hb write)
__global__ __launch_bounds__(256) void agg_pool_kernel(const unsigned short* __restrict__ fsb,
                                                       const unsigned short* __restrict__ fdb,
                                                       unsigned short* __restrict__ hb,
                                                       const int* __restrict__ offs,
                                                       const int* __restrict__ cnt,
                                                       const int* __restrict__ csr_src,
                                                       const float* __restrict__ attn_l,
                                                       const int* __restrict__ gid,
                                                       float* __restrict__ hg) {
    __shared__ float part[8 * HID];
    __shared__ int gids[8];
    int u = xcd_swz(blockIdx.x, gridDim.x);
    agg_unit<0>(u, threadIdx.x, fsb, fdb, hb, offs, cnt, csr_src, attn_l,
                gid, hg, part, gids);
}

// ---------------- D9: classifier ----------------
__global__ __launch_bounds__(256) void cls_kernel(
    const float* __restrict__ hg,
    const float* __restrict__ Wc1, const float* __restrict__ bc1,
    const float* __restrict__ Wc2, const float* __restrict__ bc2,
    const float* __restrict__ Wc3, const float* __restrict__ bc3,
    float* __restrict__ out) {
    __shared__ float xin[HID];
    __shared__ float x1[HID];
    __shared__ float x2[HID / 2];
    int g = blockIdx.x, t = threadIdx.x;
    xin[t] = hg[(size_t)g * HID + t];
    __syncthreads();
    {
        float acc = bc1[t];
        for (int k = 0; k < HID; ++k) acc += xin[k] * Wc1[k * HID + t];
        x1[t] = fmaxf(acc, 0.f);
    }
    __syncthreads();
    if (t < HID / 2) {
        float acc = bc2[t];
        for (int k = 0; k < HID; ++k) acc += x1[k] * Wc2[k * (HID / 2) + t];
        x2[t] = fmaxf(acc, 0.f);
    }
    __syncthreads();
    if (t < OUT_DIM) {
        float acc = bc3[t];
        for (int k = 0; k < HID / 2; ++k) acc += x2[k] * Wc3[k * OUT_DIM + t];
        out[g * OUT_DIM + t] = acc;
    }
}

// ---------------- launch: 10 dispatches (memset + 9 kernels) ----------------
extern "C" void kernel_launch(void* const* d_in, const int* in_sizes, int n_in,
                              void* d_out, int out_size, void* d_ws, size_t ws_size,
                              hipStream_t stream) {
    const float* feature = (const float*)d_in[0];
    const float* W_in   = (const float*)d_in[1];
    const float* b_in   = (const float*)d_in[2];
    const float* W_src  = (const float*)d_in[3];
    const float* b_src  = (const float*)d_in[4];
    const float* W_dst  = (const float*)d_in[5];
    const float* b_dst  = (const float*)d_in[6];
    const float* attn   = (const float*)d_in[7];
    const float* Wc1    = (const float*)d_in[8];
    const float* bc1    = (const float*)d_in[9];
    const float* Wc2    = (const float*)d_in[10];
    const float* bc2    = (const float*)d_in[11];
    const float* Wc3    = (const float*)d_in[12];
    const float* bc3    = (const float*)d_in[13];
    const int* src     = (const int*)d_in[14];
    const int* dst     = (const int*)d_in[15];
    const int* gid     = (const int*)d_in[16];
    float* out = (float*)d_out;

    char* w = (char*)d_ws;
    auto alloc = [&](size_t bytes) -> void* {
        void* p = (void*)w;
        w += (bytes + 255) & ~(size_t)255;
        return p;
    };
    unsigned short* hb  = (unsigned short*)alloc((size_t)N_NODES * HID * 2);  // unified bf16 h
    unsigned short* fsb = (unsigned short*)alloc((size_t)N_NODES * HID * 2);
    unsigned short* fdb = (unsigned short*)alloc((size_t)N_NODES * HID * 2);
    int* cnt     = (int*)alloc((size_t)N_BINS * 4);   // cnt + cglob + hg zeroed by one memset
    int* cglob   = (int*)alloc(4);
    float* hg    = (float*)alloc((size_t)NUM_GRAPHS * HID * 4);
    int* offs    = (int*)alloc((size_t)(N_BINS + 4) * 4);
    int* slot    = (int*)alloc((size_t)N_EDGES * 4);
    int* csr_src = (int*)alloc((size_t)N_EDGES * 4);
    unsigned short* WinT = (unsigned short*)alloc((size_t)IN_DIM * HID * 2);
    unsigned short* WT   = (unsigned short*)alloc((size_t)6 * HID * HID * 2);
    (void)alloc(4096);  // slack for clamped staging overreach

    // D0: zero cnt + cglob + hg (contiguous region, one memset)
    size_t zlen = (size_t)((char*)offs - (char*)cnt);
    hipMemsetAsync(cnt, 0, zlen, stream);

    // D1: LDS-tiled weight transposes || edge-bin count (+slot)
    hipLaunchKernelGGL(prep_count_kernel, dim3(PREP_BLOCKS + COUNT_BLOCKS), dim3(256), 0, stream,
                       W_in, W_src, W_dst, WinT, WT, src, dst, cnt, slot);

    // D2: input-projection GEMM (f32 A direct, bit-identical hb) || wide chunk scan
    hipLaunchKernelGGL(gemm0_scan_kernel, dim3(GEMM_TILES + N_CHUNKS), dim3(256), 0, stream,
                       feature, WinT, b_in, hb, cnt, cglob, offs);

    // D3: layer-0 dual GEMM || atomic-free CSR fill
    hipLaunchKernelGGL(gemm1_fill_kernel, dim3(GEMM_TILES + COUNT_BLOCKS), dim3(256), 0, stream,
                       hb, WT, b_src, fsb, WT + 3 * 65536, b_dst, fdb,
                       src, dst, offs, slot, csr_src);

    // D4..D8: agg0, gemm_l1, agg1, gemm_l2, agg_pool(l2)
    for (int l = 0; l < LAYERS; ++l) {
        if (l + 1 < LAYERS) {
            hipLaunchKernelGGL(agg_kernel, dim3(N_NODES / 8), dim3(256), 0, stream,
                               fsb, fdb, hb, offs, cnt, csr_src, attn + (size_t)l * HEADS * DH);
            hipLaunchKernelGGL(gemm_kernel, dim3(625, 2), dim3(256), 0, stream,
                               hb, WT + (size_t)(l + 1) * 65536, b_src + (size_t)(l + 1) * HID, fsb,
                               WT + (size_t)(4 + l) * 65536, b_dst + (size_t)(l + 1) * HID, fdb);
        } else {
            hipLaunchKernelGGL(agg_pool_kernel, dim3(N_NODES / 8), dim3(256), 0, stream,
                               fsb, fdb, hb, offs, cnt, csr_src, attn + (size_t)l * HEADS * DH,
                               gid, hg);
        }
    }

    // D9: classifier
    hipLaunchKernelGGL(cls_kernel, dim3(NUM_GRAPHS), dim3(256), 0, stream,
                       hg, Wc1, bc1, Wc2, bc2, Wc3, bc3, out);
}